// Round 3
// baseline (721.819 us; speedup 1.0000x reference)
//
#include <hip/hip_runtime.h>
#include <math.h>

#define Bc 2
#define Hh 32
#define Ww 32
#define Cc 384
#define NHc 12
#define NGc 6
#define CGc 64
#define HCc 32
#define GHc 2
#define HIDc 1536
#define Lc 1024
#define NSc 1024
#define BGc 12

__device__ __forceinline__ float gelu_f(float v) {
    return 0.5f * v * (1.f + erff(v * 0.70710678118654752440f));
}

// ---------------- LayerNorm over C=384, one row per 128-thread block ----
__global__ __launch_bounds__(128) void ln_kernel(
    const float* __restrict__ x, const float* __restrict__ w,
    const float* __restrict__ b, float* __restrict__ out)
{
    __shared__ float l1[2], l2[2];
    int row = blockIdx.x;
    int t = threadIdx.x;
    const float* xr = x + (size_t)row * Cc;
    float v0 = xr[t], v1 = xr[t + 128], v2 = xr[t + 256];
    float s = v0 + v1 + v2;
    #pragma unroll
    for (int o = 32; o; o >>= 1) s += __shfl_down(s, o);
    if ((t & 63) == 0) l1[t >> 6] = s;
    __syncthreads();
    float mu = (l1[0] + l1[1]) * (1.f / Cc);
    float d0 = v0 - mu, d1 = v1 - mu, d2 = v2 - mu;
    float q = d0 * d0 + d1 * d1 + d2 * d2;
    #pragma unroll
    for (int o = 32; o; o >>= 1) q += __shfl_down(q, o);
    if ((t & 63) == 0) l2[t >> 6] = q;
    __syncthreads();
    float rstd = rsqrtf((l2[0] + l2[1]) * (1.f / Cc) + 1e-5f);
    float* orow = out + (size_t)row * Cc;
    orow[t]       = d0 * rstd * w[t]       + b[t];
    orow[t + 128] = d1 * rstd * w[t + 128] + b[t + 128];
    orow[t + 256] = d2 * rstd * w[t + 256] + b[t + 256];
}

// ---------------- 64x64-tile fp32 GEMM (K-tile 32): out = W(J,K) x A ----
template<bool A_KN, bool OUT_NJ, int EPI>
__global__ __launch_bounds__(256) void gemm_kernel(
    const float* __restrict__ A, const float* __restrict__ Wt,
    const float* __restrict__ bias, const float* __restrict__ res,
    float* __restrict__ out, int N, int J, int K,
    int strideA, int strideO)
{
    __shared__ float As[32][68];   // As[k][n]
    __shared__ float Ws[32][68];   // Ws[k][j]
    int n0 = blockIdx.x * 64, j0 = blockIdx.y * 64;
    const float* Ab = A + (size_t)blockIdx.z * strideA;
    float* Ob = out + (size_t)blockIdx.z * strideO;
    const float* Rb = res + (size_t)blockIdx.z * strideO;
    int tid = threadIdx.x;
    int mg = tid & 15, jg = tid >> 4;
    float acc[4][4] = {};
    for (int k0 = 0; k0 < K; k0 += 32) {
        if (A_KN) {
            int nn = tid & 63, r0 = tid >> 6;
            #pragma unroll
            for (int i = 0; i < 8; i++)
                As[r0 + i * 4][nn] = Ab[(size_t)(k0 + r0 + i * 4) * N + n0 + nn];
        } else {
            int kk2 = tid & 31, nb = tid >> 5;
            #pragma unroll
            for (int i = 0; i < 8; i++)
                As[kk2][nb + i * 8] = Ab[(size_t)(n0 + nb + i * 8) * K + k0 + kk2];
        }
        {
            int kk2 = tid & 31, jb = tid >> 5;
            #pragma unroll
            for (int i = 0; i < 8; i++)
                Ws[kk2][jb + i * 8] = Wt[(size_t)(j0 + jb + i * 8) * K + k0 + kk2];
        }
        __syncthreads();
        #pragma unroll
        for (int kk = 0; kk < 32; kk++) {
            float4 a4 = *(const float4*)&As[kk][mg * 4];
            float4 w4 = *(const float4*)&Ws[kk][jg * 4];
            float av[4] = {a4.x, a4.y, a4.z, a4.w};
            float wv[4] = {w4.x, w4.y, w4.z, w4.w};
            #pragma unroll
            for (int i = 0; i < 4; i++)
                #pragma unroll
                for (int j = 0; j < 4; j++)
                    acc[i][j] += av[i] * wv[j];
        }
        __syncthreads();
    }
    if (OUT_NJ) {
        float4 b4 = *(const float4*)&bias[j0 + jg * 4];
        float bv[4] = {b4.x, b4.y, b4.z, b4.w};
        #pragma unroll
        for (int i = 0; i < 4; i++) {
            int n = n0 + mg * 4 + i;
            float4 v;
            float* vp = (float*)&v;
            #pragma unroll
            for (int j = 0; j < 4; j++) {
                float t2 = acc[i][j] + bv[j];
                if (EPI == 1) t2 = gelu_f(t2);
                vp[j] = t2;
            }
            size_t oi = (size_t)n * J + j0 + jg * 4;
            if (EPI == 2) {
                float4 r4 = *(const float4*)&Rb[oi];
                v.x += r4.x; v.y += r4.y; v.z += r4.z; v.w += r4.w;
            }
            *(float4*)&Ob[oi] = v;
        }
    } else {
        #pragma unroll
        for (int j = 0; j < 4; j++) {
            int jj = j0 + jg * 4 + j;
            float bv = bias[jj];
            float4 v;
            float* vp = (float*)&v;
            #pragma unroll
            for (int i = 0; i < 4; i++) {
                float t2 = acc[i][j] + bv;
                if (EPI == 1) t2 = gelu_f(t2);
                vp[i] = t2;
            }
            size_t oi = (size_t)jj * N + n0 + mg * 4;
            if (EPI == 2) {
                float4 r4 = *(const float4*)&Rb[oi];
                v.x += r4.x; v.y += r4.y; v.z += r4.z; v.w += r4.w;
            }
            *(float4*)&Ob[oi] = v;
        }
    }
}

// ---------------- Depthwise 7x7 conv (per group-channel), LDS-staged -----
__global__ __launch_bounds__(256) void dwconv_kernel(
    const float* __restrict__ q, const float* __restrict__ wdw,
    const float* __restrict__ bdw, float* __restrict__ o_dw)
{
    int cg = blockIdx.x, bg = blockIdx.y;
    int b = bg / NGc, g = bg % NGc;
    __shared__ float wk_s[49];
    __shared__ float img[1024];
    const float* qp = q + (size_t)(b * Cc + g * CGc + cg) * Lc;
    if (threadIdx.x < 49) wk_s[threadIdx.x] = wdw[cg * 49 + threadIdx.x];
    #pragma unroll
    for (int i = 0; i < 4; i++) img[threadIdx.x + i * 256] = qp[threadIdx.x + i * 256];
    __syncthreads();
    float bias = bdw[cg];
    #pragma unroll
    for (int i = 0; i < 4; i++) {
        int hw = threadIdx.x + i * 256;
        int y = hw >> 5, xx = hw & 31;
        float acc = bias;
        #pragma unroll
        for (int ky = 0; ky < 7; ky++) {
            int yy = y + ky - 3;
            if (yy < 0 || yy > 31) continue;
            #pragma unroll
            for (int kx = 0; kx < 7; kx++) {
                int x2 = xx + kx - 3;
                if (x2 < 0 || x2 > 31) continue;
                acc += img[yy * 32 + x2] * wk_s[ky * 7 + kx];
            }
        }
        o_dw[(size_t)(bg * CGc + cg) * Lc + hw] = acc;
    }
}

// ---------------- LN(CG) + GELU + pointwise -> tanh -> pos ---------------
__global__ __launch_bounds__(64) void offset_kernel(
    const float* __restrict__ o_dw, const float* __restrict__ lnw,
    const float* __restrict__ lnb, const float* __restrict__ pw,
    float* __restrict__ pos)
{
    int hw = blockIdx.x, bg = blockIdx.y;
    int cg = threadIdx.x;
    float v = o_dw[(size_t)(bg * CGc + cg) * Lc + hw];
    float s = v;
    #pragma unroll
    for (int o = 32; o; o >>= 1) s += __shfl_down(s, o);
    s = __shfl(s, 0, 64);
    float mu = s * (1.f / CGc);
    float d = v - mu;
    float q2 = d * d;
    #pragma unroll
    for (int o = 32; o; o >>= 1) q2 += __shfl_down(q2, o);
    q2 = __shfl(q2, 0, 64);
    float rstd = rsqrtf(q2 * (1.f / CGc) + 1e-5f);
    float t = d * rstd * lnw[cg] + lnb[cg];
    float gl = gelu_f(t);
    float sy = gl * pw[cg];
    float sx = gl * pw[CGc + cg];
    #pragma unroll
    for (int o = 32; o; o >>= 1) {
        sy += __shfl_down(sy, o);
        sx += __shfl_down(sx, o);
    }
    if (threadIdx.x == 0) {
        float offy = tanhf(sy) * 0.0625f;
        float offx = tanhf(sx) * 0.0625f;
        int y = hw >> 5, xx = hw & 31;
        pos[((size_t)bg * Lc + hw) * 2 + 0] = offy + ((y + 0.5f) * (2.f / Hh) - 1.f);
        pos[((size_t)bg * Lc + hw) * 2 + 1] = offx + ((xx + 0.5f) * (2.f / Ww) - 1.f);
    }
}

// ---------------- bilinear grid-sample of xn at pos -> xs (B,NS,C) -------
__global__ __launch_bounds__(256) void sample_kernel(
    const float* __restrict__ xn, const float* __restrict__ pos,
    float* __restrict__ xs)
{
    int cg = threadIdx.x & 63;
    int nl = threadIdx.x >> 6;
    int n = blockIdx.x * 4 + nl;
    int bg = blockIdx.y;
    int b = bg / NGc, g = bg % NGc;
    float py = pos[((size_t)bg * NSc + n) * 2 + 0];
    float px = pos[((size_t)bg * NSc + n) * 2 + 1];
    float fx = (px + 1.f) * 0.5f * 31.f;
    float fy = (py + 1.f) * 0.5f * 31.f;
    float x0f = floorf(fx), y0f = floorf(fy);
    int x0 = (int)x0f, y0 = (int)y0f;
    float wx1 = fx - x0f, wy1 = fy - y0f;
    float wx0 = 1.f - wx1, wy0 = 1.f - wy1;
    const float* base = xn + (size_t)(b * Lc) * Cc + g * CGc + cg;
    float acc = 0.f;
    if (y0 >= 0 && y0 <= 31) {
        if (x0 >= 0 && x0 <= 31) acc += base[(size_t)(y0 * 32 + x0) * Cc] * wx0 * wy0;
        if (x0 + 1 >= 0 && x0 + 1 <= 31) acc += base[(size_t)(y0 * 32 + x0 + 1) * Cc] * wx1 * wy0;
    }
    if (y0 + 1 >= 0 && y0 + 1 <= 31) {
        if (x0 >= 0 && x0 <= 31) acc += base[(size_t)((y0 + 1) * 32 + x0) * Cc] * wx0 * wy1;
        if (x0 + 1 >= 0 && x0 + 1 <= 31) acc += base[(size_t)((y0 + 1) * 32 + x0 + 1) * Cc] * wx1 * wy1;
    }
    xs[((size_t)(b * NSc) + n) * Cc + g * CGc + cg] = acc;
}

// ---------------- flash attention v2: block = (b, h, 32-m tile) ----------
// 256 threads. QK roles: mg=tid>>5 (4 m rows), ng=tid&31 (2 n cols):
// softmax rows live in contiguous 32-lane groups -> shuffle-only reductions.
// PV roles: wave w handles n=16w..16w+15; pm=(tid>>3)&7 (4 m), pc=tid&7 (4 c);
// per-wave partial O reduced through LDS once at the end.
__global__ __launch_bounds__(256) void attn_kernel(
    const float* __restrict__ q, const float* __restrict__ kb,
    const float* __restrict__ vb, const float* __restrict__ pos,
    const float* __restrict__ rpe, float* __restrict__ attno)
{
    __shared__ float smem[7936];
    float* q_s   = smem;            // [32][36]  (c, m)
    float* k_s   = smem + 1152;     // [32][66]  (c, n)
    float* v_t   = smem + 3264;     // [64][34]  (n, c)
    float* p_s   = smem + 5440;     // [64][36]  (n, m) xor-swizzled cols
    float* pos_y = smem + 7744;     // [64]
    float* pos_x = smem + 7808;     // [64]
    float* al_s  = smem + 7872;     // [32]
    float* l_s   = smem + 7904;     // [32]
    float* o_s   = smem + 1152;     // overlay [4][32][36] after main loop

    int m0 = blockIdx.x * 32;
    int h = blockIdx.y, b = blockIdx.z;
    int bg = b * NGc + (h >> 1);
    int tid = threadIdx.x;
    int mg = tid >> 5, ng = tid & 31;
    int w = tid >> 6;
    int pm = (tid >> 3) & 7, pc = tid & 7;

    const float* qbase = q + (size_t)(b * Cc + h * HCc) * Lc;
    {
        int mm = tid & 31, c0 = tid >> 5;
        #pragma unroll
        for (int i = 0; i < 4; i++) {
            int c = c0 + i * 8;
            q_s[c * 36 + mm] = qbase[(size_t)c * Lc + m0 + mm];
        }
    }

    float qgy[4], qgx[4];
    #pragma unroll
    for (int i = 0; i < 4; i++) {
        int m = m0 + mg * 4 + i;
        qgy[i] = ((m >> 5) + 0.5f) * (2.f / 32.f) - 1.f;
        qgx[i] = ((m & 31) + 0.5f) * (2.f / 32.f) - 1.f;
    }
    const float* tb = rpe + (size_t)h * 3969;
    const float* kbase = kb + (size_t)(b * Cc + h * HCc) * NSc;
    const float* vbase = vb + (size_t)(b * Cc + h * HCc) * NSc;
    const float* posb = pos + (size_t)bg * NSc * 2;

    float run_m[4] = {-3.0e38f, -3.0e38f, -3.0e38f, -3.0e38f};
    float run_l[4] = {0.f, 0.f, 0.f, 0.f};
    float O[4][4] = {};

    for (int n0 = 0; n0 < NSc; n0 += 64) {
        __syncthreads();   // prev tile fully consumed
        {
            int nn = tid & 63, c0 = tid >> 6;
            #pragma unroll
            for (int i = 0; i < 8; i++) {
                int c = c0 + i * 4;
                float kvv = kbase[(size_t)c * NSc + n0 + nn];
                float vvv = vbase[(size_t)c * NSc + n0 + nn];
                k_s[c * 66 + nn] = kvv;
                v_t[nn * 34 + c] = vvv;
            }
        }
        if (tid < 64) {
            pos_y[tid] = posb[2 * (n0 + tid)];
            pos_x[tid] = posb[2 * (n0 + tid) + 1];
        }
        __syncthreads();   // staging ready

        // ---- QK^T: acc[i][j], rows m0+mg*4+i, cols n0+2ng+j ----
        float acc[4][2] = {};
        #pragma unroll
        for (int c = 0; c < 32; c++) {
            float4 q4 = *(const float4*)&q_s[c * 36 + mg * 4];
            float2 k2 = *(const float2*)&k_s[c * 66 + ng * 2];
            acc[0][0] += q4.x * k2.x; acc[0][1] += q4.x * k2.y;
            acc[1][0] += q4.y * k2.x; acc[1][1] += q4.y * k2.y;
            acc[2][0] += q4.z * k2.x; acc[2][1] += q4.z * k2.y;
            acc[3][0] += q4.w * k2.x; acc[3][1] += q4.w * k2.y;
        }
        // ---- scale + RPE bilinear bias ----
        #pragma unroll
        for (int j = 0; j < 2; j++) {
            int nl = 2 * ng + j;
            float py = pos_y[nl], px = pos_x[nl];
            #pragma unroll
            for (int i = 0; i < 4; i++) {
                float fy = ((qgy[i] - py) * 0.5f + 1.f) * 31.f;
                float fx = ((qgx[i] - px) * 0.5f + 1.f) * 31.f;
                float y0f = floorf(fy), x0f = floorf(fx);
                int iy = (int)y0f, ix = (int)x0f;
                float wy1 = fy - y0f, wx1 = fx - x0f;
                float wy0 = 1.f - wy1, wx0 = 1.f - wx1;
                float bias = 0.f;
                if (iy >= 0 && iy <= 62) {
                    const float* r = tb + iy * 63;
                    if (ix >= 0 && ix <= 62) bias += r[ix] * wy0 * wx0;
                    if (ix + 1 >= 0 && ix + 1 <= 62) bias += r[ix + 1] * wy0 * wx1;
                }
                if (iy + 1 >= 0 && iy + 1 <= 62) {
                    const float* r = tb + (iy + 1) * 63;
                    if (ix >= 0 && ix <= 62) bias += r[ix] * wy1 * wx0;
                    if (ix + 1 >= 0 && ix + 1 <= 62) bias += r[ix + 1] * wy1 * wx1;
                }
                acc[i][j] = acc[i][j] * 0.17677669529663688f + bias;
            }
        }
        // ---- online softmax (width-32 shuffle groups, no barriers) ----
        float pj[4][2];
        float alpha[4];
        #pragma unroll
        for (int i = 0; i < 4; i++) {
            float mx = fmaxf(acc[i][0], acc[i][1]);
            #pragma unroll
            for (int msk = 1; msk < 32; msk <<= 1)
                mx = fmaxf(mx, __shfl_xor(mx, msk));
            float nm = fmaxf(run_m[i], mx);
            alpha[i] = expf(run_m[i] - nm);
            run_m[i] = nm;
            float p0 = expf(acc[i][0] - nm);
            float p1 = expf(acc[i][1] - nm);
            pj[i][0] = p0; pj[i][1] = p1;
            float sm = p0 + p1;
            #pragma unroll
            for (int msk = 1; msk < 32; msk <<= 1)
                sm += __shfl_xor(sm, msk);
            run_l[i] = run_l[i] * alpha[i] + sm;
        }
        // ---- write P (xor col swizzle keeps writes spread + reads b128) --
        int col4 = (mg ^ (ng & 7)) << 2;
        *(float4*)&p_s[(2 * ng) * 36 + col4] =
            make_float4(pj[0][0], pj[1][0], pj[2][0], pj[3][0]);
        *(float4*)&p_s[(2 * ng + 1) * 36 + col4] =
            make_float4(pj[0][1], pj[1][1], pj[2][1], pj[3][1]);
        if (ng == 0) {
            #pragma unroll
            for (int i = 0; i < 4; i++) al_s[mg * 4 + i] = alpha[i];
        }
        __syncthreads();   // P + alpha ready
        // ---- PV: wave-local n slice, 4x4 register tile ----
        float al[4];
        #pragma unroll
        for (int i = 0; i < 4; i++) al[i] = al_s[pm * 4 + i];
        #pragma unroll
        for (int i = 0; i < 4; i++)
            #pragma unroll
            for (int j = 0; j < 4; j++) O[i][j] *= al[i];
        #pragma unroll
        for (int nn = 0; nn < 16; nn++) {
            int n = w * 16 + nn;
            float4 p4 = *(const float4*)&p_s[n * 36 + ((pm ^ ((n >> 1) & 7)) << 2)];
            float2 va = *(const float2*)&v_t[n * 34 + pc * 4];
            float2 vb2 = *(const float2*)&v_t[n * 34 + pc * 4 + 2];
            float pv[4] = {p4.x, p4.y, p4.z, p4.w};
            float vv[4] = {va.x, va.y, vb2.x, vb2.y};
            #pragma unroll
            for (int i = 0; i < 4; i++)
                #pragma unroll
                for (int j = 0; j < 4; j++)
                    O[i][j] += pv[i] * vv[j];
        }
    }
    if (ng == 0) {
        #pragma unroll
        for (int i = 0; i < 4; i++) l_s[mg * 4 + i] = run_l[i];
    }
    __syncthreads();   // all PV reads done; l ready; o_s overlay safe
    #pragma unroll
    for (int i = 0; i < 4; i++)
        *(float4*)&o_s[w * 1152 + (pm * 4 + i) * 36 + pc * 4] =
            make_float4(O[i][0], O[i][1], O[i][2], O[i][3]);
    __syncthreads();
    {
        int mo = tid & 31, co = tid >> 5;   // co in [0,8): c = co*4..+3
        float4 s = make_float4(0.f, 0.f, 0.f, 0.f);
        #pragma unroll
        for (int ww = 0; ww < 4; ww++) {
            float4 t4 = *(const float4*)&o_s[ww * 1152 + mo * 36 + co * 4];
            s.x += t4.x; s.y += t4.y; s.z += t4.z; s.w += t4.w;
        }
        float inv = 1.f / l_s[mo];
        float sv[4] = {s.x, s.y, s.z, s.w};
        #pragma unroll
        for (int cc = 0; cc < 4; cc++)
            attno[(size_t)(b * Cc + h * HCc + co * 4 + cc) * Lc + m0 + mo] = sv[cc] * inv;
    }
}

extern "C" void kernel_launch(void* const* d_in, const int* in_sizes, int n_in,
                              void* d_out, int out_size, void* d_ws, size_t ws_size,
                              hipStream_t stream)
{
    const float* x    = (const float*)d_in[0];
    const float* n1w  = (const float*)d_in[1];
    const float* n1b  = (const float*)d_in[2];
    const float* wq   = (const float*)d_in[3];
    const float* bq   = (const float*)d_in[4];
    const float* wk   = (const float*)d_in[5];
    const float* bk   = (const float*)d_in[6];
    const float* wv   = (const float*)d_in[7];
    const float* bv   = (const float*)d_in[8];
    const float* wo   = (const float*)d_in[9];
    const float* bo   = (const float*)d_in[10];
    const float* dw_w = (const float*)d_in[11];
    const float* dw_b = (const float*)d_in[12];
    const float* lnw  = (const float*)d_in[13];
    const float* lnb  = (const float*)d_in[14];
    const float* pw_w = (const float*)d_in[15];
    const float* rpe  = (const float*)d_in[16];
    const float* n2w  = (const float*)d_in[17];
    const float* n2b  = (const float*)d_in[18];
    const float* fc1w = (const float*)d_in[19];
    const float* fc1b = (const float*)d_in[20];
    const float* fc2w = (const float*)d_in[21];
    const float* fc2b = (const float*)d_in[22];
    float* out = (float*)d_out;

    float* ws    = (float*)d_ws;
    float* xn    = ws;                 // 786432  (B,L,C)   dead after sample
    float* qb    = ws + 786432;        // 786432  (B,C,L)   dead after attn
    float* odw   = ws + 1572864;       // 786432  (BG,CG,L) dead after offset
    float* posb  = ws + 2359296;       // 24576   (BG,NS,2) dead after attn
    float* xs    = ws + 2383872;       // 786432  (B,NS,C)  dead after k/v proj
    float* kbuf  = ws + 3170304;       // 786432  (B,C,NS)
    float* vbuf  = ws + 3956736;       // 786432  (B,C,NS)
    float* attno = ws + 4743168;       // 786432  (B,C,L)
    float* x2    = ws + 5529600;       // 786432  (B,L,C)
    float* xln2  = ws + 6316032;       // 786432  (B,L,C)
    float* h1    = ws;                 // 3145728 (B*L,HID) aliases dead xn..xs

    // 1. LN1
    ln_kernel<<<Bc * Lc, 128, 0, stream>>>(x, n1w, n1b, xn);
    // 2. q projection -> (B, C, L)
    gemm_kernel<false, false, 0><<<dim3(Lc / 64, Cc / 64, Bc), 256, 0, stream>>>(
        xn, wq, bq, qb, qb, Lc, Cc, Cc, Lc * Cc, Cc * Lc);
    // 3. depthwise 7x7
    dwconv_kernel<<<dim3(CGc, BGc), 256, 0, stream>>>(qb, dw_w, dw_b, odw);
    // 4. offset head -> pos
    offset_kernel<<<dim3(Lc, BGc), 64, 0, stream>>>(odw, lnw, lnb, pw_w, posb);
    // 5. grid-sample xn -> xs (B, NS, C)
    sample_kernel<<<dim3(NSc / 4, BGc), 256, 0, stream>>>(xn, posb, xs);
    // 6/7. k, v projections -> (B, C, NS)
    gemm_kernel<false, false, 0><<<dim3(NSc / 64, Cc / 64, Bc), 256, 0, stream>>>(
        xs, wk, bk, kbuf, kbuf, NSc, Cc, Cc, NSc * Cc, Cc * NSc);
    gemm_kernel<false, false, 0><<<dim3(NSc / 64, Cc / 64, Bc), 256, 0, stream>>>(
        xs, wv, bv, vbuf, vbuf, NSc, Cc, Cc, NSc * Cc, Cc * NSc);
    // 8. flash attention (scores + rpe bias + online softmax + PV)
    attn_kernel<<<dim3(Lc / 32, NHc, Bc), 256, 0, stream>>>(qb, kbuf, vbuf, posb, rpe, attno);
    // 9. out projection + residual -> x2 (B,L,C)
    gemm_kernel<true, true, 2><<<dim3(Lc / 64, Cc / 64, Bc), 256, 0, stream>>>(
        attno, wo, bo, x, x2, Lc, Cc, Cc, Cc * Lc, Lc * Cc);
    // 10. LN2
    ln_kernel<<<Bc * Lc, 128, 0, stream>>>(x2, n2w, n2b, xln2);
    // 11. fc1 + GELU -> h1 (B*L, HID)
    gemm_kernel<false, true, 1><<<dim3(Bc * Lc / 64, HIDc / 64, 1), 256, 0, stream>>>(
        xln2, fc1w, fc1b, h1, h1, Bc * Lc, HIDc, Cc, 0, 0);
    // 12. fc2 + residual -> out
    gemm_kernel<false, true, 2><<<dim3(Bc * Lc / 64, Cc / 64, 1), 256, 0, stream>>>(
        h1, fc2w, fc2b, x2, out, Bc * Lc, Cc, HIDc, 0, 0);
}

// Round 4
// 573.060 us; speedup vs baseline: 1.2596x; 1.2596x over previous
//
#include <hip/hip_runtime.h>
#include <math.h>

#define Bc 2
#define Hh 32
#define Ww 32
#define Cc 384
#define NHc 12
#define NGc 6
#define CGc 64
#define HCc 32
#define GHc 2
#define HIDc 1536
#define Lc 1024
#define NSc 1024
#define BGc 12

typedef float f32x4 __attribute__((ext_vector_type(4)));
typedef short bf16x8 __attribute__((ext_vector_type(8)));

__device__ __forceinline__ float gelu_f(float v) {
    return 0.5f * v * (1.f + erff(v * 0.70710678118654752440f));
}

__device__ __forceinline__ unsigned short f2bf(float f) {
    unsigned u = __float_as_uint(f);
    u = (u + 0x7FFF + ((u >> 16) & 1)) >> 16;   // RNE
    return (unsigned short)u;
}

// ---------------- LayerNorm over C=384, one row per 128-thread block ----
__global__ __launch_bounds__(128) void ln_kernel(
    const float* __restrict__ x, const float* __restrict__ w,
    const float* __restrict__ b, float* __restrict__ out)
{
    __shared__ float l1[2], l2[2];
    int row = blockIdx.x;
    int t = threadIdx.x;
    const float* xr = x + (size_t)row * Cc;
    float v0 = xr[t], v1 = xr[t + 128], v2 = xr[t + 256];
    float s = v0 + v1 + v2;
    #pragma unroll
    for (int o = 32; o; o >>= 1) s += __shfl_down(s, o);
    if ((t & 63) == 0) l1[t >> 6] = s;
    __syncthreads();
    float mu = (l1[0] + l1[1]) * (1.f / Cc);
    float d0 = v0 - mu, d1 = v1 - mu, d2 = v2 - mu;
    float q = d0 * d0 + d1 * d1 + d2 * d2;
    #pragma unroll
    for (int o = 32; o; o >>= 1) q += __shfl_down(q, o);
    if ((t & 63) == 0) l2[t >> 6] = q;
    __syncthreads();
    float rstd = rsqrtf((l2[0] + l2[1]) * (1.f / Cc) + 1e-5f);
    float* orow = out + (size_t)row * Cc;
    orow[t]       = d0 * rstd * w[t]       + b[t];
    orow[t + 128] = d1 * rstd * w[t + 128] + b[t + 128];
    orow[t + 256] = d2 * rstd * w[t + 256] + b[t + 256];
}

// ---------------- 64x64-tile fp32 GEMM (K-tile 32): out = W(J,K) x A ----
// EPI: 0 none, 1 gelu, 2 residual add, 3 bf16 store (bias only)
template<bool A_KN, bool OUT_NJ, int EPI>
__global__ __launch_bounds__(256) void gemm_kernel(
    const float* __restrict__ A, const float* __restrict__ Wt,
    const float* __restrict__ bias, const float* __restrict__ res,
    float* __restrict__ out, int N, int J, int K,
    int strideA, int strideO)
{
    __shared__ float As[32][68];   // As[k][n]
    __shared__ float Ws[32][68];   // Ws[k][j]
    int n0 = blockIdx.x * 64, j0 = blockIdx.y * 64;
    const float* Ab = A + (size_t)blockIdx.z * strideA;
    float* Ob = out + (size_t)blockIdx.z * strideO;
    unsigned short* Ob16 = (unsigned short*)out + (size_t)blockIdx.z * strideO;
    const float* Rb = res + (size_t)blockIdx.z * strideO;
    int tid = threadIdx.x;
    int mg = tid & 15, jg = tid >> 4;
    float acc[4][4] = {};
    for (int k0 = 0; k0 < K; k0 += 32) {
        if (A_KN) {
            int nn = tid & 63, r0 = tid >> 6;
            #pragma unroll
            for (int i = 0; i < 8; i++)
                As[r0 + i * 4][nn] = Ab[(size_t)(k0 + r0 + i * 4) * N + n0 + nn];
        } else {
            int kk2 = tid & 31, nb = tid >> 5;
            #pragma unroll
            for (int i = 0; i < 8; i++)
                As[kk2][nb + i * 8] = Ab[(size_t)(n0 + nb + i * 8) * K + k0 + kk2];
        }
        {
            int kk2 = tid & 31, jb = tid >> 5;
            #pragma unroll
            for (int i = 0; i < 8; i++)
                Ws[kk2][jb + i * 8] = Wt[(size_t)(j0 + jb + i * 8) * K + k0 + kk2];
        }
        __syncthreads();
        #pragma unroll
        for (int kk = 0; kk < 32; kk++) {
            float4 a4 = *(const float4*)&As[kk][mg * 4];
            float4 w4 = *(const float4*)&Ws[kk][jg * 4];
            float av[4] = {a4.x, a4.y, a4.z, a4.w};
            float wv[4] = {w4.x, w4.y, w4.z, w4.w};
            #pragma unroll
            for (int i = 0; i < 4; i++)
                #pragma unroll
                for (int j = 0; j < 4; j++)
                    acc[i][j] += av[i] * wv[j];
        }
        __syncthreads();
    }
    if (OUT_NJ) {
        float4 b4 = *(const float4*)&bias[j0 + jg * 4];
        float bv[4] = {b4.x, b4.y, b4.z, b4.w};
        #pragma unroll
        for (int i = 0; i < 4; i++) {
            int n = n0 + mg * 4 + i;
            if (EPI == 3) {
                ushort4 u;
                u.x = f2bf(acc[i][0] + bv[0]); u.y = f2bf(acc[i][1] + bv[1]);
                u.z = f2bf(acc[i][2] + bv[2]); u.w = f2bf(acc[i][3] + bv[3]);
                *(ushort4*)&Ob16[(size_t)n * J + j0 + jg * 4] = u;
            } else {
                float4 v;
                float* vp = (float*)&v;
                #pragma unroll
                for (int j = 0; j < 4; j++) {
                    float t2 = acc[i][j] + bv[j];
                    if (EPI == 1) t2 = gelu_f(t2);
                    vp[j] = t2;
                }
                size_t oi = (size_t)n * J + j0 + jg * 4;
                if (EPI == 2) {
                    float4 r4 = *(const float4*)&Rb[oi];
                    v.x += r4.x; v.y += r4.y; v.z += r4.z; v.w += r4.w;
                }
                *(float4*)&Ob[oi] = v;
            }
        }
    } else {
        #pragma unroll
        for (int j = 0; j < 4; j++) {
            int jj = j0 + jg * 4 + j;
            float bv = bias[jj];
            if (EPI == 3) {
                ushort4 u;
                u.x = f2bf(acc[0][j] + bv); u.y = f2bf(acc[1][j] + bv);
                u.z = f2bf(acc[2][j] + bv); u.w = f2bf(acc[3][j] + bv);
                *(ushort4*)&Ob16[(size_t)jj * N + n0 + mg * 4] = u;
            } else {
                float4 v;
                float* vp = (float*)&v;
                #pragma unroll
                for (int i = 0; i < 4; i++) {
                    float t2 = acc[i][j] + bv;
                    if (EPI == 1) t2 = gelu_f(t2);
                    vp[i] = t2;
                }
                size_t oi = (size_t)jj * N + n0 + mg * 4;
                if (EPI == 2) {
                    float4 r4 = *(const float4*)&Rb[oi];
                    v.x += r4.x; v.y += r4.y; v.z += r4.z; v.w += r4.w;
                }
                *(float4*)&Ob[oi] = v;
            }
        }
    }
}

// ---------------- Depthwise 7x7 conv (per group-channel), LDS-staged -----
__global__ __launch_bounds__(256) void dwconv_kernel(
    const float* __restrict__ q, const float* __restrict__ wdw,
    const float* __restrict__ bdw, float* __restrict__ o_dw)
{
    int cg = blockIdx.x, bg = blockIdx.y;
    int b = bg / NGc, g = bg % NGc;
    __shared__ float wk_s[49];
    __shared__ float img[1024];
    const float* qp = q + (size_t)(b * Cc + g * CGc + cg) * Lc;
    if (threadIdx.x < 49) wk_s[threadIdx.x] = wdw[cg * 49 + threadIdx.x];
    #pragma unroll
    for (int i = 0; i < 4; i++) img[threadIdx.x + i * 256] = qp[threadIdx.x + i * 256];
    __syncthreads();
    float bias = bdw[cg];
    #pragma unroll
    for (int i = 0; i < 4; i++) {
        int hw = threadIdx.x + i * 256;
        int y = hw >> 5, xx = hw & 31;
        float acc = bias;
        #pragma unroll
        for (int ky = 0; ky < 7; ky++) {
            int yy = y + ky - 3;
            if (yy < 0 || yy > 31) continue;
            #pragma unroll
            for (int kx = 0; kx < 7; kx++) {
                int x2 = xx + kx - 3;
                if (x2 < 0 || x2 > 31) continue;
                acc += img[yy * 32 + x2] * wk_s[ky * 7 + kx];
            }
        }
        o_dw[(size_t)(bg * CGc + cg) * Lc + hw] = acc;
    }
}

// ---------------- LN(CG) + GELU + pointwise -> tanh -> pos ---------------
__global__ __launch_bounds__(64) void offset_kernel(
    const float* __restrict__ o_dw, const float* __restrict__ lnw,
    const float* __restrict__ lnb, const float* __restrict__ pw,
    float* __restrict__ pos)
{
    int hw = blockIdx.x, bg = blockIdx.y;
    int cg = threadIdx.x;
    float v = o_dw[(size_t)(bg * CGc + cg) * Lc + hw];
    float s = v;
    #pragma unroll
    for (int o = 32; o; o >>= 1) s += __shfl_down(s, o);
    s = __shfl(s, 0, 64);
    float mu = s * (1.f / CGc);
    float d = v - mu;
    float q2 = d * d;
    #pragma unroll
    for (int o = 32; o; o >>= 1) q2 += __shfl_down(q2, o);
    q2 = __shfl(q2, 0, 64);
    float rstd = rsqrtf(q2 * (1.f / CGc) + 1e-5f);
    float t = d * rstd * lnw[cg] + lnb[cg];
    float gl = gelu_f(t);
    float sy = gl * pw[cg];
    float sx = gl * pw[CGc + cg];
    #pragma unroll
    for (int o = 32; o; o >>= 1) {
        sy += __shfl_down(sy, o);
        sx += __shfl_down(sx, o);
    }
    if (threadIdx.x == 0) {
        float offy = tanhf(sy) * 0.0625f;
        float offx = tanhf(sx) * 0.0625f;
        int y = hw >> 5, xx = hw & 31;
        pos[((size_t)bg * Lc + hw) * 2 + 0] = offy + ((y + 0.5f) * (2.f / Hh) - 1.f);
        pos[((size_t)bg * Lc + hw) * 2 + 1] = offx + ((xx + 0.5f) * (2.f / Ww) - 1.f);
    }
}

// ---------------- bilinear grid-sample of xn at pos -> xs (B,NS,C) -------
__global__ __launch_bounds__(256) void sample_kernel(
    const float* __restrict__ xn, const float* __restrict__ pos,
    float* __restrict__ xs)
{
    int cg = threadIdx.x & 63;
    int nl = threadIdx.x >> 6;
    int n = blockIdx.x * 4 + nl;
    int bg = blockIdx.y;
    int b = bg / NGc, g = bg % NGc;
    float py = pos[((size_t)bg * NSc + n) * 2 + 0];
    float px = pos[((size_t)bg * NSc + n) * 2 + 1];
    float fx = (px + 1.f) * 0.5f * 31.f;
    float fy = (py + 1.f) * 0.5f * 31.f;
    float x0f = floorf(fx), y0f = floorf(fy);
    int x0 = (int)x0f, y0 = (int)y0f;
    float wx1 = fx - x0f, wy1 = fy - y0f;
    float wx0 = 1.f - wx1, wy0 = 1.f - wy1;
    const float* base = xn + (size_t)(b * Lc) * Cc + g * CGc + cg;
    float acc = 0.f;
    if (y0 >= 0 && y0 <= 31) {
        if (x0 >= 0 && x0 <= 31) acc += base[(size_t)(y0 * 32 + x0) * Cc] * wx0 * wy0;
        if (x0 + 1 >= 0 && x0 + 1 <= 31) acc += base[(size_t)(y0 * 32 + x0 + 1) * Cc] * wx1 * wy0;
    }
    if (y0 + 1 >= 0 && y0 + 1 <= 31) {
        if (x0 >= 0 && x0 <= 31) acc += base[(size_t)((y0 + 1) * 32 + x0) * Cc] * wx0 * wy1;
        if (x0 + 1 >= 0 && x0 + 1 <= 31) acc += base[(size_t)((y0 + 1) * 32 + x0 + 1) * Cc] * wx1 * wy1;
    }
    xs[((size_t)(b * NSc) + n) * Cc + g * CGc + cg] = acc;
}

// ---------------- transpose-cast q: (B,C,L) fp32 -> (B,NH,L,32) bf16 -----
__global__ __launch_bounds__(256) void qt_kernel(
    const float* __restrict__ qb, unsigned short* __restrict__ qbf)
{
    __shared__ float t[32][33];
    int m0 = blockIdx.x * 32, h = blockIdx.y, b = blockIdx.z;
    int tx = threadIdx.x & 31, ty = threadIdx.x >> 5;
    #pragma unroll
    for (int i = 0; i < 4; i++) {
        int c = ty + i * 8;
        t[c][tx] = qb[(size_t)(b * Cc + h * 32 + c) * Lc + m0 + tx];
    }
    __syncthreads();
    #pragma unroll
    for (int i = 0; i < 4; i++) {
        int m = ty + i * 8;
        qbf[(((size_t)(b * NHc + h)) * Lc + m0 + m) * 32 + tx] = f2bf(t[tx][m]);
    }
}

// ---------------- MFMA flash attention: one wave per 16 m-rows -----------
// qbf (B,NH,L,32) bf16; kbf (B,NS,C) bf16; vtb (B,C,NS) bf16.
// S-tile 16m x 64n per iter: 4 QK MFMAs (C-layout: m=quad*4+r, n=col+16ch),
// softmax via 16-lane xor shuffles (rows confined to a quad), P -> LDS bf16
// (A-layout round trip), 4 PV MFMAs. No __syncthreads anywhere.
__global__ __launch_bounds__(64) void attn_kernel(
    const unsigned short* __restrict__ qbf, const unsigned short* __restrict__ kbf,
    const unsigned short* __restrict__ vtb, const float* __restrict__ pos,
    const float* __restrict__ rpe, float* __restrict__ attno)
{
    __shared__ unsigned short p_bf[16 * 72];   // [m][n] row-pad 72
    int m0 = blockIdx.x * 16;
    int h = blockIdx.y, b = blockIdx.z;
    int l = threadIdx.x;
    int col = l & 15, quad = l >> 4;

    bf16x8 qfrag = *(const bf16x8*)(qbf +
        ((((size_t)(b * NHc + h)) * Lc + m0 + col) * 32 + quad * 8));

    float qgy[4], qgx[4];
    #pragma unroll
    for (int r = 0; r < 4; r++) {
        int m = m0 + quad * 4 + r;
        qgy[r] = ((m >> 5) + 0.5f) * (2.f / 32.f) - 1.f;
        qgx[r] = ((m & 31) + 0.5f) * (2.f / 32.f) - 1.f;
    }
    const float* tb = rpe + (size_t)h * 3969;
    const unsigned short* kb_ = kbf + (size_t)b * NSc * Cc + h * HCc;
    const unsigned short* vb_ = vtb + ((size_t)(b * Cc + h * HCc)) * NSc;
    const float2* pp = (const float2*)(pos + (size_t)(b * NGc + (h >> 1)) * NSc * 2);

    float run_m[4] = {-3.0e38f, -3.0e38f, -3.0e38f, -3.0e38f};
    float run_l[4] = {0.f, 0.f, 0.f, 0.f};
    f32x4 O0 = {0.f, 0.f, 0.f, 0.f};
    f32x4 O1 = {0.f, 0.f, 0.f, 0.f};

    for (int n0 = 0; n0 < NSc; n0 += 64) {
        // ---- QK^T (4 n-chunks of 16) ----
        f32x4 s[4];
        #pragma unroll
        for (int ch = 0; ch < 4; ch++) {
            bf16x8 kf = *(const bf16x8*)(kb_ +
                ((size_t)(n0 + ch * 16 + col) * Cc + quad * 8));
            f32x4 z = {0.f, 0.f, 0.f, 0.f};
            s[ch] = __builtin_amdgcn_mfma_f32_16x16x32_bf16(qfrag, kf, z, 0, 0, 0);
        }
        // ---- scale + RPE bilinear bias ----
        #pragma unroll
        for (int ch = 0; ch < 4; ch++) {
            int n = n0 + ch * 16 + col;
            float2 pyx = pp[n];
            #pragma unroll
            for (int r = 0; r < 4; r++) {
                float fy = ((qgy[r] - pyx.x) * 0.5f + 1.f) * 31.f;
                float fx = ((qgx[r] - pyx.y) * 0.5f + 1.f) * 31.f;
                float y0f = floorf(fy), x0f = floorf(fx);
                int iy = (int)y0f, ix = (int)x0f;
                float wy1 = fy - y0f, wx1 = fx - x0f;
                float wy0 = 1.f - wy1, wx0 = 1.f - wx1;
                float bias = 0.f;
                if (iy >= 0 && iy <= 62) {
                    const float* rr = tb + iy * 63;
                    if (ix >= 0 && ix <= 62) bias += rr[ix] * wy0 * wx0;
                    if (ix + 1 >= 0 && ix + 1 <= 62) bias += rr[ix + 1] * wy0 * wx1;
                }
                if (iy + 1 >= 0 && iy + 1 <= 62) {
                    const float* rr = tb + (iy + 1) * 63;
                    if (ix >= 0 && ix <= 62) bias += rr[ix] * wy1 * wx0;
                    if (ix + 1 >= 0 && ix + 1 <= 62) bias += rr[ix + 1] * wy1 * wx1;
                }
                s[ch][r] = s[ch][r] * 0.17677669529663688f + bias;
            }
        }
        // ---- online softmax: rows m=quad*4+r live in this quad's 16 lanes --
        float nm[4], alpha[4];
        #pragma unroll
        for (int r = 0; r < 4; r++) {
            float mx = fmaxf(fmaxf(s[0][r], s[1][r]), fmaxf(s[2][r], s[3][r]));
            #pragma unroll
            for (int msk = 1; msk < 16; msk <<= 1)
                mx = fmaxf(mx, __shfl_xor(mx, msk));
            nm[r] = fmaxf(run_m[r], mx);
            alpha[r] = expf(run_m[r] - nm[r]);
            run_m[r] = nm[r];
        }
        float rowsum[4] = {0.f, 0.f, 0.f, 0.f};
        #pragma unroll
        for (int ch = 0; ch < 4; ch++)
            #pragma unroll
            for (int r = 0; r < 4; r++) {
                float e = expf(s[ch][r] - nm[r]);
                s[ch][r] = e;
                rowsum[r] += e;
            }
        #pragma unroll
        for (int r = 0; r < 4; r++) {
            float sm = rowsum[r];
            #pragma unroll
            for (int msk = 1; msk < 16; msk <<= 1)
                sm += __shfl_xor(sm, msk);
            run_l[r] = run_l[r] * alpha[r] + sm;
        }
        // ---- P -> LDS (C-layout regs -> A-layout rows), wave-private ----
        #pragma unroll
        for (int ch = 0; ch < 4; ch++)
            #pragma unroll
            for (int r = 0; r < 4; r++)
                p_bf[(quad * 4 + r) * 72 + ch * 16 + col] = f2bf(s[ch][r]);
        // ---- rescale O, then PV (2 n-halves x 2 c-chunks) ----
        #pragma unroll
        for (int r = 0; r < 4; r++) { O0[r] *= alpha[r]; O1[r] *= alpha[r]; }
        #pragma unroll
        for (int half = 0; half < 2; half++) {
            bf16x8 pf = *(const bf16x8*)&p_bf[col * 72 + half * 32 + quad * 8];
            bf16x8 v0 = *(const bf16x8*)(vb_ +
                ((size_t)col * NSc + n0 + half * 32 + quad * 8));
            O0 = __builtin_amdgcn_mfma_f32_16x16x32_bf16(pf, v0, O0, 0, 0, 0);
            bf16x8 v1 = *(const bf16x8*)(vb_ +
                ((size_t)(col + 16) * NSc + n0 + half * 32 + quad * 8));
            O1 = __builtin_amdgcn_mfma_f32_16x16x32_bf16(pf, v1, O1, 0, 0, 0);
        }
    }
    // ---- epilogue: normalize + store attno (B,C,L) fp32 ----
    #pragma unroll
    for (int r = 0; r < 4; r++) {
        float inv = 1.f / run_l[r];
        int m = m0 + quad * 4 + r;
        attno[(size_t)(b * Cc + h * HCc + col) * Lc + m] = O0[r] * inv;
        attno[(size_t)(b * Cc + h * HCc + col + 16) * Lc + m] = O1[r] * inv;
    }
}

extern "C" void kernel_launch(void* const* d_in, const int* in_sizes, int n_in,
                              void* d_out, int out_size, void* d_ws, size_t ws_size,
                              hipStream_t stream)
{
    const float* x    = (const float*)d_in[0];
    const float* n1w  = (const float*)d_in[1];
    const float* n1b  = (const float*)d_in[2];
    const float* wq   = (const float*)d_in[3];
    const float* bq   = (const float*)d_in[4];
    const float* wk   = (const float*)d_in[5];
    const float* bk   = (const float*)d_in[6];
    const float* wv   = (const float*)d_in[7];
    const float* bv   = (const float*)d_in[8];
    const float* wo   = (const float*)d_in[9];
    const float* bo   = (const float*)d_in[10];
    const float* dw_w = (const float*)d_in[11];
    const float* dw_b = (const float*)d_in[12];
    const float* lnw  = (const float*)d_in[13];
    const float* lnb  = (const float*)d_in[14];
    const float* pw_w = (const float*)d_in[15];
    const float* rpe  = (const float*)d_in[16];
    const float* n2w  = (const float*)d_in[17];
    const float* n2b  = (const float*)d_in[18];
    const float* fc1w = (const float*)d_in[19];
    const float* fc1b = (const float*)d_in[20];
    const float* fc2w = (const float*)d_in[21];
    const float* fc2b = (const float*)d_in[22];
    float* out = (float*)d_out;

    float* ws    = (float*)d_ws;
    float* xn    = ws;                 // 786432 f  (B,L,C)   dead after sample
    float* qb    = ws + 786432;        // 786432 f  (B,C,L)
    float* odw   = ws + 1572864;       // 786432 f  (BG,CG,L)
    float* posb  = ws + 2359296;       // 24576  f  (BG,NS,2)
    float* xs    = ws + 2383872;       // 786432 f  (B,NS,C)
    unsigned short* kbf = (unsigned short*)(ws + 3170304);  // 786432 us (B,NS,C)
    unsigned short* vtb = (unsigned short*)(ws + 3563520);  // 786432 us (B,C,NS)
    unsigned short* qbf = (unsigned short*)(ws + 3956736);  // 786432 us (B,NH,L,32)
    float* attno = ws + 4743168;       // 786432 f  (B,C,L)
    float* x2    = ws + 5529600;       // 786432 f  (B,L,C)
    float* xln2  = ws + 6316032;       // 786432 f  (B,L,C)
    float* h1    = ws;                 // 3145728 f (B*L,HID) aliases dead xn..xs

    // 1. LN1
    ln_kernel<<<Bc * Lc, 128, 0, stream>>>(x, n1w, n1b, xn);
    // 2. q projection -> (B, C, L) fp32
    gemm_kernel<false, false, 0><<<dim3(Lc / 64, Cc / 64, Bc), 256, 0, stream>>>(
        xn, wq, bq, qb, qb, Lc, Cc, Cc, Lc * Cc, Cc * Lc);
    // 2b. transpose-cast q -> (B,NH,L,32) bf16
    qt_kernel<<<dim3(Lc / 32, NHc, Bc), 256, 0, stream>>>(qb, qbf);
    // 3. depthwise 7x7
    dwconv_kernel<<<dim3(CGc, BGc), 256, 0, stream>>>(qb, dw_w, dw_b, odw);
    // 4. offset head -> pos
    offset_kernel<<<dim3(Lc, BGc), 64, 0, stream>>>(odw, lnw, lnb, pw_w, posb);
    // 5. grid-sample xn -> xs (B, NS, C)
    sample_kernel<<<dim3(NSc / 4, BGc), 256, 0, stream>>>(xn, posb, xs);
    // 6. k projection -> bf16 (B, NS, C)
    gemm_kernel<false, true, 3><<<dim3(NSc / 64, Cc / 64, Bc), 256, 0, stream>>>(
        xs, wk, bk, (float*)kbf, (float*)kbf, NSc, Cc, Cc, NSc * Cc, NSc * Cc);
    // 7. v projection -> bf16 (B, C, NS)
    gemm_kernel<false, false, 3><<<dim3(NSc / 64, Cc / 64, Bc), 256, 0, stream>>>(
        xs, wv, bv, (float*)vtb, (float*)vtb, NSc, Cc, Cc, NSc * Cc, Cc * NSc);
    // 8. MFMA flash attention
    attn_kernel<<<dim3(Lc / 16, NHc, Bc), 64, 0, stream>>>(
        qbf, kbf, vtb, posb, rpe, attno);
    // 9. out projection + residual -> x2 (B,L,C)
    gemm_kernel<true, true, 2><<<dim3(Lc / 64, Cc / 64, Bc), 256, 0, stream>>>(
        attno, wo, bo, x, x2, Lc, Cc, Cc, Cc * Lc, Lc * Cc);
    // 10. LN2
    ln_kernel<<<Bc * Lc, 128, 0, stream>>>(x2, n2w, n2b, xln2);
    // 11. fc1 + GELU -> h1 (B*L, HID)
    gemm_kernel<false, true, 1><<<dim3(Bc * Lc / 64, HIDc / 64, 1), 256, 0, stream>>>(
        xln2, fc1w, fc1b, h1, h1, Bc * Lc, HIDc, Cc, 0, 0);
    // 12. fc2 + residual -> out
    gemm_kernel<false, true, 2><<<dim3(Bc * Lc / 64, Cc / 64, 1), 256, 0, stream>>>(
        h1, fc2w, fc2b, x2, out, Bc * Lc, Cc, HIDc, 0, 0);
}

// Round 5
// 388.507 us; speedup vs baseline: 1.8579x; 1.4750x over previous
//
#include <hip/hip_runtime.h>
#include <math.h>

#define Bc 2
#define Hh 32
#define Ww 32
#define Cc 384
#define NHc 12
#define NGc 6
#define CGc 64
#define HCc 32
#define GHc 2
#define HIDc 1536
#define Lc 1024
#define NSc 1024
#define BGc 12

typedef float f32x4 __attribute__((ext_vector_type(4)));
typedef short bf16x8 __attribute__((ext_vector_type(8)));

__device__ __forceinline__ float gelu_f(float v) {
    return 0.5f * v * (1.f + erff(v * 0.70710678118654752440f));
}

__device__ __forceinline__ unsigned short f2bf(float f) {
    unsigned u = __float_as_uint(f);
    u = (u + 0x7FFF + ((u >> 16) & 1)) >> 16;   // RNE
    return (unsigned short)u;
}

// ---------------- LayerNorm over C=384, one row per 128-thread block ----
// BF16OUT: store bf16 (ushort) rows instead of f32
template<bool BF16OUT>
__global__ __launch_bounds__(128) void ln_kernel(
    const float* __restrict__ x, const float* __restrict__ w,
    const float* __restrict__ b, void* __restrict__ outv)
{
    __shared__ float l1[2], l2[2];
    int row = blockIdx.x;
    int t = threadIdx.x;
    const float* xr = x + (size_t)row * Cc;
    float v0 = xr[t], v1 = xr[t + 128], v2 = xr[t + 256];
    float s = v0 + v1 + v2;
    #pragma unroll
    for (int o = 32; o; o >>= 1) s += __shfl_down(s, o);
    if ((t & 63) == 0) l1[t >> 6] = s;
    __syncthreads();
    float mu = (l1[0] + l1[1]) * (1.f / Cc);
    float d0 = v0 - mu, d1 = v1 - mu, d2 = v2 - mu;
    float q = d0 * d0 + d1 * d1 + d2 * d2;
    #pragma unroll
    for (int o = 32; o; o >>= 1) q += __shfl_down(q, o);
    if ((t & 63) == 0) l2[t >> 6] = q;
    __syncthreads();
    float rstd = rsqrtf((l2[0] + l2[1]) * (1.f / Cc) + 1e-5f);
    float o0 = d0 * rstd * w[t]       + b[t];
    float o1 = d1 * rstd * w[t + 128] + b[t + 128];
    float o2 = d2 * rstd * w[t + 256] + b[t + 256];
    if (BF16OUT) {
        unsigned short* orow = (unsigned short*)outv + (size_t)row * Cc;
        orow[t] = f2bf(o0); orow[t + 128] = f2bf(o1); orow[t + 256] = f2bf(o2);
    } else {
        float* orow = (float*)outv + (size_t)row * Cc;
        orow[t] = o0; orow[t + 128] = o1; orow[t + 256] = o2;
    }
}

// ---------------- f32 -> bf16 cast --------------------------------------
__global__ __launch_bounds__(256) void cast_kernel(
    const float* __restrict__ src, unsigned short* __restrict__ dst, int n)
{
    int i = blockIdx.x * 1024 + threadIdx.x * 4;
    if (i < n) {
        float4 v = *(const float4*)(src + i);
        ushort4 u;
        u.x = f2bf(v.x); u.y = f2bf(v.y); u.z = f2bf(v.z); u.w = f2bf(v.w);
        *(ushort4*)(dst + i) = u;
    }
}

// ---------------- 64x64-tile fp32 GEMM (K-tile 32): out = W(J,K) x A ----
// EPI: 0 none, 1 gelu, 2 residual add, 3 bf16 store (bias only)
template<bool A_KN, bool OUT_NJ, int EPI>
__global__ __launch_bounds__(256) void gemm_kernel(
    const float* __restrict__ A, const float* __restrict__ Wt,
    const float* __restrict__ bias, const float* __restrict__ res,
    float* __restrict__ out, int N, int J, int K,
    int strideA, int strideO)
{
    __shared__ float As[32][68];   // As[k][n]
    __shared__ float Ws[32][68];   // Ws[k][j]
    int n0 = blockIdx.x * 64, j0 = blockIdx.y * 64;
    const float* Ab = A + (size_t)blockIdx.z * strideA;
    float* Ob = out + (size_t)blockIdx.z * strideO;
    unsigned short* Ob16 = (unsigned short*)out + (size_t)blockIdx.z * strideO;
    const float* Rb = res + (size_t)blockIdx.z * strideO;
    int tid = threadIdx.x;
    int mg = tid & 15, jg = tid >> 4;
    float acc[4][4] = {};
    for (int k0 = 0; k0 < K; k0 += 32) {
        if (A_KN) {
            int nn = tid & 63, r0 = tid >> 6;
            #pragma unroll
            for (int i = 0; i < 8; i++)
                As[r0 + i * 4][nn] = Ab[(size_t)(k0 + r0 + i * 4) * N + n0 + nn];
        } else {
            int kk2 = tid & 31, nb = tid >> 5;
            #pragma unroll
            for (int i = 0; i < 8; i++)
                As[kk2][nb + i * 8] = Ab[(size_t)(n0 + nb + i * 8) * K + k0 + kk2];
        }
        {
            int kk2 = tid & 31, jb = tid >> 5;
            #pragma unroll
            for (int i = 0; i < 8; i++)
                Ws[kk2][jb + i * 8] = Wt[(size_t)(j0 + jb + i * 8) * K + k0 + kk2];
        }
        __syncthreads();
        #pragma unroll
        for (int kk = 0; kk < 32; kk++) {
            float4 a4 = *(const float4*)&As[kk][mg * 4];
            float4 w4 = *(const float4*)&Ws[kk][jg * 4];
            float av[4] = {a4.x, a4.y, a4.z, a4.w};
            float wv[4] = {w4.x, w4.y, w4.z, w4.w};
            #pragma unroll
            for (int i = 0; i < 4; i++)
                #pragma unroll
                for (int j = 0; j < 4; j++)
                    acc[i][j] += av[i] * wv[j];
        }
        __syncthreads();
    }
    if (OUT_NJ) {
        float4 b4 = *(const float4*)&bias[j0 + jg * 4];
        float bv[4] = {b4.x, b4.y, b4.z, b4.w};
        #pragma unroll
        for (int i = 0; i < 4; i++) {
            int n = n0 + mg * 4 + i;
            if (EPI == 3) {
                ushort4 u;
                u.x = f2bf(acc[i][0] + bv[0]); u.y = f2bf(acc[i][1] + bv[1]);
                u.z = f2bf(acc[i][2] + bv[2]); u.w = f2bf(acc[i][3] + bv[3]);
                *(ushort4*)&Ob16[(size_t)n * J + j0 + jg * 4] = u;
            } else {
                float4 v;
                float* vp = (float*)&v;
                #pragma unroll
                for (int j = 0; j < 4; j++) {
                    float t2 = acc[i][j] + bv[j];
                    if (EPI == 1) t2 = gelu_f(t2);
                    vp[j] = t2;
                }
                size_t oi = (size_t)n * J + j0 + jg * 4;
                if (EPI == 2) {
                    float4 r4 = *(const float4*)&Rb[oi];
                    v.x += r4.x; v.y += r4.y; v.z += r4.z; v.w += r4.w;
                }
                *(float4*)&Ob[oi] = v;
            }
        }
    } else {
        #pragma unroll
        for (int j = 0; j < 4; j++) {
            int jj = j0 + jg * 4 + j;
            float bv = bias[jj];
            if (EPI == 3) {
                ushort4 u;
                u.x = f2bf(acc[0][j] + bv); u.y = f2bf(acc[1][j] + bv);
                u.z = f2bf(acc[2][j] + bv); u.w = f2bf(acc[3][j] + bv);
                *(ushort4*)&Ob16[(size_t)jj * N + n0 + mg * 4] = u;
            } else {
                float4 v;
                float* vp = (float*)&v;
                #pragma unroll
                for (int i = 0; i < 4; i++) {
                    float t2 = acc[i][j] + bv;
                    if (EPI == 1) t2 = gelu_f(t2);
                    vp[i] = t2;
                }
                size_t oi = (size_t)jj * N + n0 + mg * 4;
                if (EPI == 2) {
                    float4 r4 = *(const float4*)&Rb[oi];
                    v.x += r4.x; v.y += r4.y; v.z += r4.z; v.w += r4.w;
                }
                *(float4*)&Ob[oi] = v;
            }
        }
    }
}

// ---------------- bf16 MFMA GEMM: out(M,N) = A(M,K) x W(N,K)^T ----------
// 4 waves/block; wave w owns 16 m-rows; 64-n tile; frags straight from global.
// EPI: 1 = gelu -> bf16 out; 2 = +bias +res -> f32 out
template<int EPI>
__global__ __launch_bounds__(256) void mfma_gemm(
    const unsigned short* __restrict__ A, const unsigned short* __restrict__ W,
    const float* __restrict__ bias, const float* __restrict__ res,
    void* __restrict__ outv, int M, int N, int K)
{
    int w = threadIdx.x >> 6, l = threadIdx.x & 63;
    int col = l & 15, quad = l >> 4;
    int mb = blockIdx.x * 64 + w * 16;
    int n0 = blockIdx.y * 64;
    const unsigned short* Ap = A + (size_t)(mb + col) * K + quad * 8;
    f32x4 acc[4] = {};
    for (int k0 = 0; k0 < K; k0 += 32) {
        bf16x8 af = *(const bf16x8*)(Ap + k0);
        #pragma unroll
        for (int ch = 0; ch < 4; ch++) {
            bf16x8 wf = *(const bf16x8*)(W + (size_t)(n0 + ch * 16 + col) * K + k0 + quad * 8);
            acc[ch] = __builtin_amdgcn_mfma_f32_16x16x32_bf16(af, wf, acc[ch], 0, 0, 0);
        }
    }
    #pragma unroll
    for (int ch = 0; ch < 4; ch++) {
        int n = n0 + ch * 16 + col;
        float bv = bias[n];
        #pragma unroll
        for (int r = 0; r < 4; r++) {
            int m = mb + quad * 4 + r;
            float v = acc[ch][r] + bv;
            if (EPI == 1) {
                ((unsigned short*)outv)[(size_t)m * N + n] = f2bf(gelu_f(v));
            } else {
                v += res[(size_t)m * N + n];
                ((float*)outv)[(size_t)m * N + n] = v;
            }
        }
    }
}

// ---------------- Depthwise 7x7 conv (per group-channel), LDS-staged -----
__global__ __launch_bounds__(256) void dwconv_kernel(
    const float* __restrict__ q, const float* __restrict__ wdw,
    const float* __restrict__ bdw, float* __restrict__ o_dw)
{
    int cg = blockIdx.x, bg = blockIdx.y;
    int b = bg / NGc, g = bg % NGc;
    __shared__ float wk_s[49];
    __shared__ float img[1024];
    const float* qp = q + (size_t)(b * Cc + g * CGc + cg) * Lc;
    if (threadIdx.x < 49) wk_s[threadIdx.x] = wdw[cg * 49 + threadIdx.x];
    #pragma unroll
    for (int i = 0; i < 4; i++) img[threadIdx.x + i * 256] = qp[threadIdx.x + i * 256];
    __syncthreads();
    float bias = bdw[cg];
    #pragma unroll
    for (int i = 0; i < 4; i++) {
        int hw = threadIdx.x + i * 256;
        int y = hw >> 5, xx = hw & 31;
        float acc = bias;
        #pragma unroll
        for (int ky = 0; ky < 7; ky++) {
            int yy = y + ky - 3;
            if (yy < 0 || yy > 31) continue;
            #pragma unroll
            for (int kx = 0; kx < 7; kx++) {
                int x2 = xx + kx - 3;
                if (x2 < 0 || x2 > 31) continue;
                acc += img[yy * 32 + x2] * wk_s[ky * 7 + kx];
            }
        }
        o_dw[(size_t)(bg * CGc + cg) * Lc + hw] = acc;
    }
}

// ---------------- LN(CG) + GELU + pointwise -> tanh -> pos ---------------
__global__ __launch_bounds__(64) void offset_kernel(
    const float* __restrict__ o_dw, const float* __restrict__ lnw,
    const float* __restrict__ lnb, const float* __restrict__ pw,
    float* __restrict__ pos)
{
    int hw = blockIdx.x, bg = blockIdx.y;
    int cg = threadIdx.x;
    float v = o_dw[(size_t)(bg * CGc + cg) * Lc + hw];
    float s = v;
    #pragma unroll
    for (int o = 32; o; o >>= 1) s += __shfl_down(s, o);
    s = __shfl(s, 0, 64);
    float mu = s * (1.f / CGc);
    float d = v - mu;
    float q2 = d * d;
    #pragma unroll
    for (int o = 32; o; o >>= 1) q2 += __shfl_down(q2, o);
    q2 = __shfl(q2, 0, 64);
    float rstd = rsqrtf(q2 * (1.f / CGc) + 1e-5f);
    float t = d * rstd * lnw[cg] + lnb[cg];
    float gl = gelu_f(t);
    float sy = gl * pw[cg];
    float sx = gl * pw[CGc + cg];
    #pragma unroll
    for (int o = 32; o; o >>= 1) {
        sy += __shfl_down(sy, o);
        sx += __shfl_down(sx, o);
    }
    if (threadIdx.x == 0) {
        float offy = tanhf(sy) * 0.0625f;
        float offx = tanhf(sx) * 0.0625f;
        int y = hw >> 5, xx = hw & 31;
        pos[((size_t)bg * Lc + hw) * 2 + 0] = offy + ((y + 0.5f) * (2.f / Hh) - 1.f);
        pos[((size_t)bg * Lc + hw) * 2 + 1] = offx + ((xx + 0.5f) * (2.f / Ww) - 1.f);
    }
}

// ---------------- bilinear grid-sample of xn at pos -> xs (B,NS,C) -------
__global__ __launch_bounds__(256) void sample_kernel(
    const float* __restrict__ xn, const float* __restrict__ pos,
    float* __restrict__ xs)
{
    int cg = threadIdx.x & 63;
    int nl = threadIdx.x >> 6;
    int n = blockIdx.x * 4 + nl;
    int bg = blockIdx.y;
    int b = bg / NGc, g = bg % NGc;
    float py = pos[((size_t)bg * NSc + n) * 2 + 0];
    float px = pos[((size_t)bg * NSc + n) * 2 + 1];
    float fx = (px + 1.f) * 0.5f * 31.f;
    float fy = (py + 1.f) * 0.5f * 31.f;
    float x0f = floorf(fx), y0f = floorf(fy);
    int x0 = (int)x0f, y0 = (int)y0f;
    float wx1 = fx - x0f, wy1 = fy - y0f;
    float wx0 = 1.f - wx1, wy0 = 1.f - wy1;
    const float* base = xn + (size_t)(b * Lc) * Cc + g * CGc + cg;
    float acc = 0.f;
    if (y0 >= 0 && y0 <= 31) {
        if (x0 >= 0 && x0 <= 31) acc += base[(size_t)(y0 * 32 + x0) * Cc] * wx0 * wy0;
        if (x0 + 1 >= 0 && x0 + 1 <= 31) acc += base[(size_t)(y0 * 32 + x0 + 1) * Cc] * wx1 * wy0;
    }
    if (y0 + 1 >= 0 && y0 + 1 <= 31) {
        if (x0 >= 0 && x0 <= 31) acc += base[(size_t)((y0 + 1) * 32 + x0) * Cc] * wx0 * wy1;
        if (x0 + 1 >= 0 && x0 + 1 <= 31) acc += base[(size_t)((y0 + 1) * 32 + x0 + 1) * Cc] * wx1 * wy1;
    }
    xs[((size_t)(b * NSc) + n) * Cc + g * CGc + cg] = acc;
}

// ---------------- transpose-cast q: (B,C,L) fp32 -> (B,NH,L,32) bf16 -----
__global__ __launch_bounds__(256) void qt_kernel(
    const float* __restrict__ qb, unsigned short* __restrict__ qbf)
{
    __shared__ float t[32][33];
    int m0 = blockIdx.x * 32, h = blockIdx.y, b = blockIdx.z;
    int tx = threadIdx.x & 31, ty = threadIdx.x >> 5;
    #pragma unroll
    for (int i = 0; i < 4; i++) {
        int c = ty + i * 8;
        t[c][tx] = qb[(size_t)(b * Cc + h * 32 + c) * Lc + m0 + tx];
    }
    __syncthreads();
    #pragma unroll
    for (int i = 0; i < 4; i++) {
        int m = ty + i * 8;
        qbf[(((size_t)(b * NHc + h)) * Lc + m0 + m) * 32 + tx] = f2bf(t[tx][m]);
    }
}

// ---------------- MFMA flash attention v2 --------------------------------
// Block = 256 thr (4 waves) per (b, h, 16 m-rows). Wave w covers n in
// [w*256, w*256+256). RPE table staged in LDS (63x64). Per-wave online
// softmax; cross-wave merge (m,l,O) via LDS at the end.
__global__ __launch_bounds__(256) void attn_kernel(
    const unsigned short* __restrict__ qbf, const unsigned short* __restrict__ kbf,
    const unsigned short* __restrict__ vtb, const float* __restrict__ pos,
    const float* __restrict__ rpe, float* __restrict__ attno)
{
    __shared__ float rpe_s[63 * 64];            // 16128 B; o_s overlays after loop
    __shared__ unsigned short p_bf[4][16 * 72]; // per-wave P tile
    __shared__ float ml_s[4][2][16];
    float* o_s = rpe_s;                          // [4][16][33]

    int m0 = blockIdx.x * 16;
    int h = blockIdx.y, b = blockIdx.z;
    int tid = threadIdx.x;
    int w = tid >> 6, l = tid & 63;
    int col = l & 15, quad = l >> 4;

    const float* tb = rpe + (size_t)h * 3969;
    for (int i = tid; i < 63 * 64; i += 256) {
        int row = i >> 6, cx = i & 63;
        rpe_s[i] = (cx < 63) ? tb[row * 63 + cx] : 0.f;
    }

    bf16x8 qfrag = *(const bf16x8*)(qbf +
        ((((size_t)(b * NHc + h)) * Lc + m0 + col) * 32 + quad * 8));

    // m>>5 constant across the 16-row tile; fx affine in r with step 31/32
    float qgy = ((m0 >> 5) + 0.5f) * (2.f / 32.f) - 1.f;
    float qgx0 = (((m0 & 31) + quad * 4) + 0.5f) * (2.f / 32.f) - 1.f;

    const unsigned short* kb_ = kbf + (size_t)b * NSc * Cc + h * HCc;
    const unsigned short* vb_ = vtb + ((size_t)(b * Cc + h * HCc)) * NSc;
    const float2* pp = (const float2*)(pos + (size_t)(b * NGc + (h >> 1)) * NSc * 2);

    float run_m[4] = {-3.0e38f, -3.0e38f, -3.0e38f, -3.0e38f};
    float run_l[4] = {0.f, 0.f, 0.f, 0.f};
    f32x4 O0 = {0.f, 0.f, 0.f, 0.f};
    f32x4 O1 = {0.f, 0.f, 0.f, 0.f};

    __syncthreads();   // rpe_s staged

    for (int it = 0; it < 4; it++) {
        int n0 = w * 256 + it * 64;
        // ---- QK^T ----
        f32x4 s[4];
        #pragma unroll
        for (int ch = 0; ch < 4; ch++) {
            bf16x8 kf = *(const bf16x8*)(kb_ +
                ((size_t)(n0 + ch * 16 + col) * Cc + quad * 8));
            f32x4 z = {0.f, 0.f, 0.f, 0.f};
            s[ch] = __builtin_amdgcn_mfma_f32_16x16x32_bf16(qfrag, kf, z, 0, 0, 0);
        }
        // ---- scale + RPE bias (LDS bilinear; fy hoisted, fx affine in r) --
        #pragma unroll
        for (int ch = 0; ch < 4; ch++) {
            int n = n0 + ch * 16 + col;
            float2 pyx = pp[n];
            float fy = ((qgy - pyx.x) * 0.5f + 1.f) * 31.f;
            float y0f = floorf(fy);
            int iy = (int)y0f;
            float wy1 = fy - y0f, wy0 = 1.f - wy1;
            bool y0ok = (unsigned)iy <= 62u;
            bool y1ok = (unsigned)(iy + 1) <= 62u;
            const float* r0 = rpe_s + iy * 64;
            float fx0 = ((qgx0 - pyx.y) * 0.5f + 1.f) * 31.f;
            #pragma unroll
            for (int r = 0; r < 4; r++) {
                float fx = fx0 + r * 0.96875f;
                float x0f = floorf(fx);
                int ix = (int)x0f;
                float wx1 = fx - x0f, wx0 = 1.f - wx1;
                bool x0ok = (unsigned)ix <= 62u;
                bool x1ok = (unsigned)(ix + 1) <= 62u;
                float bias = 0.f;
                if (y0ok) {
                    if (x0ok) bias += r0[ix] * wy0 * wx0;
                    if (x1ok) bias += r0[ix + 1] * wy0 * wx1;
                }
                if (y1ok) {
                    if (x0ok) bias += r0[64 + ix] * wy1 * wx0;
                    if (x1ok) bias += r0[64 + ix + 1] * wy1 * wx1;
                }
                s[ch][r] = s[ch][r] * 0.17677669529663688f + bias;
            }
        }
        // ---- online softmax (16-lane xor shuffles within quad) ----
        float nm[4], alpha[4];
        #pragma unroll
        for (int r = 0; r < 4; r++) {
            float mx = fmaxf(fmaxf(s[0][r], s[1][r]), fmaxf(s[2][r], s[3][r]));
            #pragma unroll
            for (int msk = 1; msk < 16; msk <<= 1)
                mx = fmaxf(mx, __shfl_xor(mx, msk));
            nm[r] = fmaxf(run_m[r], mx);
            alpha[r] = expf(run_m[r] - nm[r]);
            run_m[r] = nm[r];
        }
        float rowsum[4] = {0.f, 0.f, 0.f, 0.f};
        #pragma unroll
        for (int ch = 0; ch < 4; ch++)
            #pragma unroll
            for (int r = 0; r < 4; r++) {
                float e = expf(s[ch][r] - nm[r]);
                s[ch][r] = e;
                rowsum[r] += e;
            }
        #pragma unroll
        for (int r = 0; r < 4; r++) {
            float sm = rowsum[r];
            #pragma unroll
            for (int msk = 1; msk < 16; msk <<= 1)
                sm += __shfl_xor(sm, msk);
            run_l[r] = run_l[r] * alpha[r] + sm;
        }
        // ---- P -> wave-private LDS (C-layout -> A-layout) ----
        #pragma unroll
        for (int ch = 0; ch < 4; ch++)
            #pragma unroll
            for (int r = 0; r < 4; r++)
                p_bf[w][(quad * 4 + r) * 72 + ch * 16 + col] = f2bf(s[ch][r]);
        // ---- rescale O, PV ----
        #pragma unroll
        for (int r = 0; r < 4; r++) { O0[r] *= alpha[r]; O1[r] *= alpha[r]; }
        #pragma unroll
        for (int half = 0; half < 2; half++) {
            bf16x8 pf = *(const bf16x8*)&p_bf[w][col * 72 + half * 32 + quad * 8];
            bf16x8 v0 = *(const bf16x8*)(vb_ +
                ((size_t)col * NSc + n0 + half * 32 + quad * 8));
            O0 = __builtin_amdgcn_mfma_f32_16x16x32_bf16(pf, v0, O0, 0, 0, 0);
            bf16x8 v1 = *(const bf16x8*)(vb_ +
                ((size_t)(col + 16) * NSc + n0 + half * 32 + quad * 8));
            O1 = __builtin_amdgcn_mfma_f32_16x16x32_bf16(pf, v1, O1, 0, 0, 0);
        }
    }
    __syncthreads();   // all rpe_s reads done before o_s overlay
    #pragma unroll
    for (int r = 0; r < 4; r++) {
        int m = quad * 4 + r;
        o_s[w * 528 + m * 33 + col] = O0[r];
        o_s[w * 528 + m * 33 + col + 16] = O1[r];
    }
    if (col == 0) {
        #pragma unroll
        for (int r = 0; r < 4; r++) {
            ml_s[w][0][quad * 4 + r] = run_m[r];
            ml_s[w][1][quad * 4 + r] = run_l[r];
        }
    }
    __syncthreads();
    // ---- cross-wave merge: 16 m x 32 c over 256 threads ----
    for (int i = tid; i < 512; i += 256) {
        int m = i >> 5, c = i & 31;
        float fm = fmaxf(fmaxf(ml_s[0][0][m], ml_s[1][0][m]),
                         fmaxf(ml_s[2][0][m], ml_s[3][0][m]));
        float lsum = 0.f, osum = 0.f;
        #pragma unroll
        for (int ww = 0; ww < 4; ww++) {
            float sc = expf(ml_s[ww][0][m] - fm);
            lsum += ml_s[ww][1][m] * sc;
            osum += o_s[ww * 528 + m * 33 + c] * sc;
        }
        attno[(size_t)(b * Cc + h * HCc + c) * Lc + m0 + m] = osum / lsum;
    }
}

extern "C" void kernel_launch(void* const* d_in, const int* in_sizes, int n_in,
                              void* d_out, int out_size, void* d_ws, size_t ws_size,
                              hipStream_t stream)
{
    const float* x    = (const float*)d_in[0];
    const float* n1w  = (const float*)d_in[1];
    const float* n1b  = (const float*)d_in[2];
    const float* wq   = (const float*)d_in[3];
    const float* bq   = (const float*)d_in[4];
    const float* wk   = (const float*)d_in[5];
    const float* bk   = (const float*)d_in[6];
    const float* wv   = (const float*)d_in[7];
    const float* bv   = (const float*)d_in[8];
    const float* wo   = (const float*)d_in[9];
    const float* bo   = (const float*)d_in[10];
    const float* dw_w = (const float*)d_in[11];
    const float* dw_b = (const float*)d_in[12];
    const float* lnw  = (const float*)d_in[13];
    const float* lnb  = (const float*)d_in[14];
    const float* pw_w = (const float*)d_in[15];
    const float* rpe  = (const float*)d_in[16];
    const float* n2w  = (const float*)d_in[17];
    const float* n2b  = (const float*)d_in[18];
    const float* fc1w = (const float*)d_in[19];
    const float* fc1b = (const float*)d_in[20];
    const float* fc2w = (const float*)d_in[21];
    const float* fc2b = (const float*)d_in[22];
    float* out = (float*)d_out;

    float* ws = (float*)d_ws;
    // live-range-aware layout (floats):
    float* xn    = ws;                 // [0, 786432)       dead after sample
    float* qb    = ws + 786432;        // [786432, 1572864) dead after dwconv/qt
    float* odw   = ws + 1572864;       // [1572864,2359296) dead after offset
    float* posb  = ws + 2359296;       // [2359296,2383872) dead after attn
    float* xs    = ws + 2383872;       // [2383872,3170304) dead after k/v proj
    unsigned short* kbf = (unsigned short*)(ws + 3170304);  // (B,NS,C) bf16
    unsigned short* vtb = (unsigned short*)(ws + 3563520);  // (B,C,NS) bf16
    unsigned short* qbf = (unsigned short*)(ws + 3956736);  // (B,NH,L,32) bf16
    float* attno = ws + 4349952;       // (B,C,L) f32
    float* x2    = ws + 5136384;       // (B,L,C) f32
    unsigned short* xln2bf = (unsigned short*)(ws + 1572864);  // overlays odw
    unsigned short* h1bf   = (unsigned short*)ws;              // overlays xn+qb
    unsigned short* fc1wbf = (unsigned short*)(ws + 2383872);  // overlays xs
    unsigned short* fc2wbf = (unsigned short*)(ws + 2678784);  // overlays xs

    // 1. LN1 -> xn f32
    ln_kernel<false><<<Bc * Lc, 128, 0, stream>>>(x, n1w, n1b, xn);
    // 2. q projection -> (B, C, L) fp32
    gemm_kernel<false, false, 0><<<dim3(Lc / 64, Cc / 64, Bc), 256, 0, stream>>>(
        xn, wq, bq, qb, qb, Lc, Cc, Cc, Lc * Cc, Cc * Lc);
    // 2b. transpose-cast q -> (B,NH,L,32) bf16
    qt_kernel<<<dim3(Lc / 32, NHc, Bc), 256, 0, stream>>>(qb, qbf);
    // 3. depthwise 7x7
    dwconv_kernel<<<dim3(CGc, BGc), 256, 0, stream>>>(qb, dw_w, dw_b, odw);
    // 4. offset head -> pos
    offset_kernel<<<dim3(Lc, BGc), 64, 0, stream>>>(odw, lnw, lnb, pw_w, posb);
    // 5. grid-sample xn -> xs (B, NS, C)
    sample_kernel<<<dim3(NSc / 4, BGc), 256, 0, stream>>>(xn, posb, xs);
    // 6. k projection -> bf16 (B, NS, C)
    gemm_kernel<false, true, 3><<<dim3(NSc / 64, Cc / 64, Bc), 256, 0, stream>>>(
        xs, wk, bk, (float*)kbf, (float*)kbf, NSc, Cc, Cc, NSc * Cc, NSc * Cc);
    // 7. v projection -> bf16 (B, C, NS)
    gemm_kernel<false, false, 3><<<dim3(NSc / 64, Cc / 64, Bc), 256, 0, stream>>>(
        xs, wv, bv, (float*)vtb, (float*)vtb, NSc, Cc, Cc, NSc * Cc, Cc * NSc);
    // 7b. weight casts (xs now dead; regions overlay it)
    cast_kernel<<<(Cc * HIDc + 1023) / 1024, 256, 0, stream>>>(fc1w, fc1wbf, Cc * HIDc);
    cast_kernel<<<(Cc * HIDc + 1023) / 1024, 256, 0, stream>>>(fc2w, fc2wbf, Cc * HIDc);
    // 8. MFMA flash attention (4 waves/block, n-split, LDS rpe)
    attn_kernel<<<dim3(Lc / 16, NHc, Bc), 256, 0, stream>>>(
        qbf, kbf, vtb, posb, rpe, attno);
    // 9. out projection + residual -> x2 (B,L,C) f32
    gemm_kernel<true, true, 2><<<dim3(Lc / 64, Cc / 64, Bc), 256, 0, stream>>>(
        attno, wo, bo, x, x2, Lc, Cc, Cc, Cc * Lc, Lc * Cc);
    // 10. LN2 -> bf16
    ln_kernel<true><<<Bc * Lc, 128, 0, stream>>>(x2, n2w, n2b, xln2bf);
    // 11. fc1 + GELU -> h1 bf16 (MFMA)
    mfma_gemm<1><<<dim3(Bc * Lc / 64, HIDc / 64), 256, 0, stream>>>(
        xln2bf, fc1wbf, fc1b, x2, h1bf, Bc * Lc, HIDc, Cc);
    // 12. fc2 + residual -> out f32 (MFMA)
    mfma_gemm<2><<<dim3(Bc * Lc / 64, Cc / 64), 256, 0, stream>>>(
        h1bf, fc2wbf, fc2b, x2, out, Bc * Lc, Cc, HIDc);
}

// Round 6
// 331.838 us; speedup vs baseline: 2.1752x; 1.1708x over previous
//
#include <hip/hip_runtime.h>
#include <math.h>

#define Bc 2
#define Hh 32
#define Ww 32
#define Cc 384
#define NHc 12
#define NGc 6
#define CGc 64
#define HCc 32
#define GHc 2
#define HIDc 1536
#define Lc 1024
#define NSc 1024
#define BGc 12

typedef float f32x4 __attribute__((ext_vector_type(4)));
typedef short bf16x8 __attribute__((ext_vector_type(8)));

__device__ __forceinline__ float gelu_f(float v) {
    return 0.5f * v * (1.f + erff(v * 0.70710678118654752440f));
}

__device__ __forceinline__ unsigned short f2bf(float f) {
    unsigned u = __float_as_uint(f);
    u = (u + 0x7FFF + ((u >> 16) & 1)) >> 16;   // RNE
    return (unsigned short)u;
}

__device__ __forceinline__ float bf2f(unsigned short u) {
    return __uint_as_float((unsigned)u << 16);
}

// ---------------- LayerNorm over C=384 -> bf16, one row per 128 thr -----
__global__ __launch_bounds__(128) void ln_kernel(
    const float* __restrict__ x, const float* __restrict__ w,
    const float* __restrict__ b, unsigned short* __restrict__ out)
{
    __shared__ float l1[2], l2[2];
    int row = blockIdx.x;
    int t = threadIdx.x;
    const float* xr = x + (size_t)row * Cc;
    float v0 = xr[t], v1 = xr[t + 128], v2 = xr[t + 256];
    float s = v0 + v1 + v2;
    #pragma unroll
    for (int o = 32; o; o >>= 1) s += __shfl_down(s, o);
    if ((t & 63) == 0) l1[t >> 6] = s;
    __syncthreads();
    float mu = (l1[0] + l1[1]) * (1.f / Cc);
    float d0 = v0 - mu, d1 = v1 - mu, d2 = v2 - mu;
    float q = d0 * d0 + d1 * d1 + d2 * d2;
    #pragma unroll
    for (int o = 32; o; o >>= 1) q += __shfl_down(q, o);
    if ((t & 63) == 0) l2[t >> 6] = q;
    __syncthreads();
    float rstd = rsqrtf((l2[0] + l2[1]) * (1.f / Cc) + 1e-5f);
    unsigned short* orow = out + (size_t)row * Cc;
    orow[t]       = f2bf(d0 * rstd * w[t]       + b[t]);
    orow[t + 128] = f2bf(d1 * rstd * w[t + 128] + b[t + 128]);
    orow[t + 256] = f2bf(d2 * rstd * w[t + 256] + b[t + 256]);
}

// ---------------- f32 -> bf16 cast --------------------------------------
__global__ __launch_bounds__(256) void cast_kernel(
    const float* __restrict__ src, unsigned short* __restrict__ dst, int n)
{
    int i = blockIdx.x * 1024 + threadIdx.x * 4;
    if (i < n) {
        float4 v = *(const float4*)(src + i);
        ushort4 u;
        u.x = f2bf(v.x); u.y = f2bf(v.y); u.z = f2bf(v.z); u.w = f2bf(v.w);
        *(ushort4*)(dst + i) = u;
    }
}

// ---------------- bf16 MFMA GEMM: out(M,N) = A(M,K) x W(N,K)^T + bias ---
// 4 waves/block; wave w owns 16 m-rows x 64 n-cols; frags from global.
// EPI 1: gelu -> bf16 out1[m*N+n]
// EPI 2: + res[m*N+n] -> f32 out1[m*N+n]
// EPI 3: dual q-store: out1 f32 (B,C,L), out2 bf16 (B,NH,L,32)  (b=m>>10)
// EPI 4: bf16 out1[m*N+n]
// EPI 5: bf16 transposed out1 (B,C,NS)  (b=m>>10)
template<int EPI>
__global__ __launch_bounds__(256) void mfma_gemm(
    const unsigned short* __restrict__ A, const unsigned short* __restrict__ W,
    const float* __restrict__ bias, const float* __restrict__ res,
    void* __restrict__ out1, void* __restrict__ out2, int M, int N, int K)
{
    int w = threadIdx.x >> 6, l = threadIdx.x & 63;
    int col = l & 15, quad = l >> 4;
    int mb = blockIdx.x * 64 + w * 16;
    int n0 = blockIdx.y * 64;
    const unsigned short* Ap = A + (size_t)(mb + col) * K + quad * 8;
    f32x4 acc[4] = {};
    for (int k0 = 0; k0 < K; k0 += 32) {
        bf16x8 af = *(const bf16x8*)(Ap + k0);
        #pragma unroll
        for (int ch = 0; ch < 4; ch++) {
            bf16x8 wf = *(const bf16x8*)(W + (size_t)(n0 + ch * 16 + col) * K + k0 + quad * 8);
            acc[ch] = __builtin_amdgcn_mfma_f32_16x16x32_bf16(af, wf, acc[ch], 0, 0, 0);
        }
    }
    int bb = mb >> 10, l0 = (mb & 1023) + quad * 4;
    #pragma unroll
    for (int ch = 0; ch < 4; ch++) {
        int n = n0 + ch * 16 + col;
        float bv = bias[n];
        if (EPI == 3) {
            float4 qv;
            qv.x = acc[ch][0] + bv; qv.y = acc[ch][1] + bv;
            qv.z = acc[ch][2] + bv; qv.w = acc[ch][3] + bv;
            *(float4*)&((float*)out1)[((size_t)(bb * Cc + n)) * Lc + l0] = qv;
            unsigned short* q2 = (unsigned short*)out2;
            size_t base = (((size_t)(bb * NHc + (n >> 5))) * Lc + l0) * 32 + (n & 31);
            q2[base]      = f2bf(qv.x);
            q2[base + 32] = f2bf(qv.y);
            q2[base + 64] = f2bf(qv.z);
            q2[base + 96] = f2bf(qv.w);
        } else if (EPI == 5) {
            ushort4 u;
            u.x = f2bf(acc[ch][0] + bv); u.y = f2bf(acc[ch][1] + bv);
            u.z = f2bf(acc[ch][2] + bv); u.w = f2bf(acc[ch][3] + bv);
            *(ushort4*)&((unsigned short*)out1)[((size_t)(bb * Cc + n)) * NSc + l0] = u;
        } else {
            #pragma unroll
            for (int r = 0; r < 4; r++) {
                size_t m = mb + quad * 4 + r;
                float v = acc[ch][r] + bv;
                if (EPI == 1)
                    ((unsigned short*)out1)[m * N + n] = f2bf(gelu_f(v));
                else if (EPI == 4)
                    ((unsigned short*)out1)[m * N + n] = f2bf(v);
                else
                    ((float*)out1)[m * N + n] = v + res[m * N + n];
            }
        }
    }
}

// ---------------- Depthwise 7x7 conv (per group-channel), LDS-staged -----
__global__ __launch_bounds__(256) void dwconv_kernel(
    const float* __restrict__ q, const float* __restrict__ wdw,
    const float* __restrict__ bdw, float* __restrict__ o_dw)
{
    int cg = blockIdx.x, bg = blockIdx.y;
    int b = bg / NGc, g = bg % NGc;
    __shared__ float wk_s[49];
    __shared__ float img[1024];
    const float* qp = q + (size_t)(b * Cc + g * CGc + cg) * Lc;
    if (threadIdx.x < 49) wk_s[threadIdx.x] = wdw[cg * 49 + threadIdx.x];
    #pragma unroll
    for (int i = 0; i < 4; i++) img[threadIdx.x + i * 256] = qp[threadIdx.x + i * 256];
    __syncthreads();
    float bias = bdw[cg];
    #pragma unroll
    for (int i = 0; i < 4; i++) {
        int hw = threadIdx.x + i * 256;
        int y = hw >> 5, xx = hw & 31;
        float acc = bias;
        #pragma unroll
        for (int ky = 0; ky < 7; ky++) {
            int yy = y + ky - 3;
            if (yy < 0 || yy > 31) continue;
            #pragma unroll
            for (int kx = 0; kx < 7; kx++) {
                int x2 = xx + kx - 3;
                if (x2 < 0 || x2 > 31) continue;
                acc += img[yy * 32 + x2] * wk_s[ky * 7 + kx];
            }
        }
        o_dw[(size_t)(bg * CGc + cg) * Lc + hw] = acc;
    }
}

// ---------------- LN(CG) + GELU + pointwise -> tanh -> pos ---------------
__global__ __launch_bounds__(64) void offset_kernel(
    const float* __restrict__ o_dw, const float* __restrict__ lnw,
    const float* __restrict__ lnb, const float* __restrict__ pw,
    float* __restrict__ pos)
{
    int hw = blockIdx.x, bg = blockIdx.y;
    int cg = threadIdx.x;
    float v = o_dw[(size_t)(bg * CGc + cg) * Lc + hw];
    float s = v;
    #pragma unroll
    for (int o = 32; o; o >>= 1) s += __shfl_down(s, o);
    s = __shfl(s, 0, 64);
    float mu = s * (1.f / CGc);
    float d = v - mu;
    float q2 = d * d;
    #pragma unroll
    for (int o = 32; o; o >>= 1) q2 += __shfl_down(q2, o);
    q2 = __shfl(q2, 0, 64);
    float rstd = rsqrtf(q2 * (1.f / CGc) + 1e-5f);
    float t = d * rstd * lnw[cg] + lnb[cg];
    float gl = gelu_f(t);
    float sy = gl * pw[cg];
    float sx = gl * pw[CGc + cg];
    #pragma unroll
    for (int o = 32; o; o >>= 1) {
        sy += __shfl_down(sy, o);
        sx += __shfl_down(sx, o);
    }
    if (threadIdx.x == 0) {
        float offy = tanhf(sy) * 0.0625f;
        float offx = tanhf(sx) * 0.0625f;
        int y = hw >> 5, xx = hw & 31;
        pos[((size_t)bg * Lc + hw) * 2 + 0] = offy + ((y + 0.5f) * (2.f / Hh) - 1.f);
        pos[((size_t)bg * Lc + hw) * 2 + 1] = offx + ((xx + 0.5f) * (2.f / Ww) - 1.f);
    }
}

// ---------------- bilinear grid-sample of xn(bf16) at pos -> xs bf16 -----
__global__ __launch_bounds__(256) void sample_kernel(
    const unsigned short* __restrict__ xn, const float* __restrict__ pos,
    unsigned short* __restrict__ xs)
{
    int cg = threadIdx.x & 63;
    int nl = threadIdx.x >> 6;
    int n = blockIdx.x * 4 + nl;
    int bg = blockIdx.y;
    int b = bg / NGc, g = bg % NGc;
    float py = pos[((size_t)bg * NSc + n) * 2 + 0];
    float px = pos[((size_t)bg * NSc + n) * 2 + 1];
    float fx = (px + 1.f) * 0.5f * 31.f;
    float fy = (py + 1.f) * 0.5f * 31.f;
    float x0f = floorf(fx), y0f = floorf(fy);
    int x0 = (int)x0f, y0 = (int)y0f;
    float wx1 = fx - x0f, wy1 = fy - y0f;
    float wx0 = 1.f - wx1, wy0 = 1.f - wy1;
    const unsigned short* base = xn + (size_t)(b * Lc) * Cc + g * CGc + cg;
    float acc = 0.f;
    if (y0 >= 0 && y0 <= 31) {
        if (x0 >= 0 && x0 <= 31) acc += bf2f(base[(size_t)(y0 * 32 + x0) * Cc]) * wx0 * wy0;
        if (x0 + 1 >= 0 && x0 + 1 <= 31) acc += bf2f(base[(size_t)(y0 * 32 + x0 + 1) * Cc]) * wx1 * wy0;
    }
    if (y0 + 1 >= 0 && y0 + 1 <= 31) {
        if (x0 >= 0 && x0 <= 31) acc += bf2f(base[(size_t)((y0 + 1) * 32 + x0) * Cc]) * wx0 * wy1;
        if (x0 + 1 >= 0 && x0 + 1 <= 31) acc += bf2f(base[(size_t)((y0 + 1) * 32 + x0 + 1) * Cc]) * wx1 * wy1;
    }
    xs[((size_t)(b * NSc) + n) * Cc + g * CGc + cg] = f2bf(acc);
}

// ---------------- MFMA flash attention v3 --------------------------------
// Block = 256 thr (4 waves) per (b, h, 16 m-rows). Wave w covers n in
// [w*256, w*256+256). RPE staged in LDS with 65-pad rows (bank spread).
// Output bf16 (B,L,C) for the MFMA out-projection.
__global__ __launch_bounds__(256) void attn_kernel(
    const unsigned short* __restrict__ qbf, const unsigned short* __restrict__ kbf,
    const unsigned short* __restrict__ vtb, const float* __restrict__ pos,
    const float* __restrict__ rpe, unsigned short* __restrict__ attno)
{
    __shared__ float rpe_s[63 * 65];            // 16380 B; o_s overlays after loop
    __shared__ unsigned short p_bf[4][16 * 72]; // per-wave P tile
    __shared__ float ml_s[4][2][16];
    float* o_s = rpe_s;                          // [4][16][33]

    int m0 = blockIdx.x * 16;
    int h = blockIdx.y, b = blockIdx.z;
    int tid = threadIdx.x;
    int w = tid >> 6, l = tid & 63;
    int col = l & 15, quad = l >> 4;

    const float* tb = rpe + (size_t)h * 3969;
    for (int i = tid; i < 63 * 65; i += 256) {
        int row = i / 65, cx = i - row * 65;
        rpe_s[i] = (cx < 63) ? tb[row * 63 + cx] : 0.f;
    }

    bf16x8 qfrag = *(const bf16x8*)(qbf +
        ((((size_t)(b * NHc + h)) * Lc + m0 + col) * 32 + quad * 8));

    float qgy = ((m0 >> 5) + 0.5f) * (2.f / 32.f) - 1.f;
    float qgx0 = (((m0 & 31) + quad * 4) + 0.5f) * (2.f / 32.f) - 1.f;

    const unsigned short* kb_ = kbf + (size_t)b * NSc * Cc + h * HCc;
    const unsigned short* vb_ = vtb + ((size_t)(b * Cc + h * HCc)) * NSc;
    const float2* pp = (const float2*)(pos + (size_t)(b * NGc + (h >> 1)) * NSc * 2);

    float run_m[4] = {-3.0e38f, -3.0e38f, -3.0e38f, -3.0e38f};
    float run_l[4] = {0.f, 0.f, 0.f, 0.f};
    f32x4 O0 = {0.f, 0.f, 0.f, 0.f};
    f32x4 O1 = {0.f, 0.f, 0.f, 0.f};

    __syncthreads();   // rpe_s staged

    for (int it = 0; it < 4; it++) {
        int n0 = w * 256 + it * 64;
        // ---- QK^T ----
        f32x4 s[4];
        #pragma unroll
        for (int ch = 0; ch < 4; ch++) {
            bf16x8 kf = *(const bf16x8*)(kb_ +
                ((size_t)(n0 + ch * 16 + col) * Cc + quad * 8));
            f32x4 z = {0.f, 0.f, 0.f, 0.f};
            s[ch] = __builtin_amdgcn_mfma_f32_16x16x32_bf16(qfrag, kf, z, 0, 0, 0);
        }
        // ---- scale + RPE bias (LDS bilinear; fy hoisted, fx affine in r) --
        #pragma unroll
        for (int ch = 0; ch < 4; ch++) {
            int n = n0 + ch * 16 + col;
            float2 pyx = pp[n];
            float fy = ((qgy - pyx.x) * 0.5f + 1.f) * 31.f;
            float y0f = floorf(fy);
            int iy = (int)y0f;
            float wy1 = fy - y0f, wy0 = 1.f - wy1;
            bool y0ok = (unsigned)iy <= 62u;
            bool y1ok = (unsigned)(iy + 1) <= 62u;
            const float* r0 = rpe_s + iy * 65;
            float fx0 = ((qgx0 - pyx.y) * 0.5f + 1.f) * 31.f;
            #pragma unroll
            for (int r = 0; r < 4; r++) {
                float fx = fx0 + r * 0.96875f;
                float x0f = floorf(fx);
                int ix = (int)x0f;
                float wx1 = fx - x0f, wx0 = 1.f - wx1;
                bool x0ok = (unsigned)ix <= 62u;
                bool x1ok = (unsigned)(ix + 1) <= 62u;
                float bias = 0.f;
                if (y0ok) {
                    if (x0ok) bias += r0[ix] * wy0 * wx0;
                    if (x1ok) bias += r0[ix + 1] * wy0 * wx1;
                }
                if (y1ok) {
                    if (x0ok) bias += r0[65 + ix] * wy1 * wx0;
                    if (x1ok) bias += r0[65 + ix + 1] * wy1 * wx1;
                }
                s[ch][r] = s[ch][r] * 0.17677669529663688f + bias;
            }
        }
        // ---- online softmax (16-lane xor shuffles within quad) ----
        float nm[4], alpha[4];
        #pragma unroll
        for (int r = 0; r < 4; r++) {
            float mx = fmaxf(fmaxf(s[0][r], s[1][r]), fmaxf(s[2][r], s[3][r]));
            #pragma unroll
            for (int msk = 1; msk < 16; msk <<= 1)
                mx = fmaxf(mx, __shfl_xor(mx, msk));
            nm[r] = fmaxf(run_m[r], mx);
            alpha[r] = expf(run_m[r] - nm[r]);
            run_m[r] = nm[r];
        }
        float rowsum[4] = {0.f, 0.f, 0.f, 0.f};
        #pragma unroll
        for (int ch = 0; ch < 4; ch++)
            #pragma unroll
            for (int r = 0; r < 4; r++) {
                float e = expf(s[ch][r] - nm[r]);
                s[ch][r] = e;
                rowsum[r] += e;
            }
        #pragma unroll
        for (int r = 0; r < 4; r++) {
            float sm = rowsum[r];
            #pragma unroll
            for (int msk = 1; msk < 16; msk <<= 1)
                sm += __shfl_xor(sm, msk);
            run_l[r] = run_l[r] * alpha[r] + sm;
        }
        // ---- P -> wave-private LDS (C-layout -> A-layout) ----
        #pragma unroll
        for (int ch = 0; ch < 4; ch++)
            #pragma unroll
            for (int r = 0; r < 4; r++)
                p_bf[w][(quad * 4 + r) * 72 + ch * 16 + col] = f2bf(s[ch][r]);
        // ---- rescale O, PV ----
        #pragma unroll
        for (int r = 0; r < 4; r++) { O0[r] *= alpha[r]; O1[r] *= alpha[r]; }
        #pragma unroll
        for (int half = 0; half < 2; half++) {
            bf16x8 pf = *(const bf16x8*)&p_bf[w][col * 72 + half * 32 + quad * 8];
            bf16x8 v0 = *(const bf16x8*)(vb_ +
                ((size_t)col * NSc + n0 + half * 32 + quad * 8));
            O0 = __builtin_amdgcn_mfma_f32_16x16x32_bf16(pf, v0, O0, 0, 0, 0);
            bf16x8 v1 = *(const bf16x8*)(vb_ +
                ((size_t)(col + 16) * NSc + n0 + half * 32 + quad * 8));
            O1 = __builtin_amdgcn_mfma_f32_16x16x32_bf16(pf, v1, O1, 0, 0, 0);
        }
    }
    __syncthreads();   // all rpe_s reads done before o_s overlay
    #pragma unroll
    for (int r = 0; r < 4; r++) {
        int m = quad * 4 + r;
        o_s[w * 528 + m * 33 + col] = O0[r];
        o_s[w * 528 + m * 33 + col + 16] = O1[r];
    }
    if (col == 0) {
        #pragma unroll
        for (int r = 0; r < 4; r++) {
            ml_s[w][0][quad * 4 + r] = run_m[r];
            ml_s[w][1][quad * 4 + r] = run_l[r];
        }
    }
    __syncthreads();
    // ---- cross-wave merge -> bf16 (B,L,C) ----
    for (int i = tid; i < 512; i += 256) {
        int m = i >> 5, c = i & 31;
        float fm = fmaxf(fmaxf(ml_s[0][0][m], ml_s[1][0][m]),
                         fmaxf(ml_s[2][0][m], ml_s[3][0][m]));
        float lsum = 0.f, osum = 0.f;
        #pragma unroll
        for (int ww = 0; ww < 4; ww++) {
            float sc = expf(ml_s[ww][0][m] - fm);
            lsum += ml_s[ww][1][m] * sc;
            osum += o_s[ww * 528 + m * 33 + c] * sc;
        }
        attno[((size_t)(b * Lc) + m0 + m) * Cc + h * HCc + c] = f2bf(osum / lsum);
    }
}

extern "C" void kernel_launch(void* const* d_in, const int* in_sizes, int n_in,
                              void* d_out, int out_size, void* d_ws, size_t ws_size,
                              hipStream_t stream)
{
    const float* x    = (const float*)d_in[0];
    const float* n1w  = (const float*)d_in[1];
    const float* n1b  = (const float*)d_in[2];
    const float* wq   = (const float*)d_in[3];
    const float* bq   = (const float*)d_in[4];
    const float* wk   = (const float*)d_in[5];
    const float* bk   = (const float*)d_in[6];
    const float* wv   = (const float*)d_in[7];
    const float* bv   = (const float*)d_in[8];
    const float* wo   = (const float*)d_in[9];
    const float* bo   = (const float*)d_in[10];
    const float* dw_w = (const float*)d_in[11];
    const float* dw_b = (const float*)d_in[12];
    const float* lnw  = (const float*)d_in[13];
    const float* lnb  = (const float*)d_in[14];
    const float* pw_w = (const float*)d_in[15];
    const float* rpe  = (const float*)d_in[16];
    const float* n2w  = (const float*)d_in[17];
    const float* n2b  = (const float*)d_in[18];
    const float* fc1w = (const float*)d_in[19];
    const float* fc1b = (const float*)d_in[20];
    const float* fc2w = (const float*)d_in[21];
    const float* fc2b = (const float*)d_in[22];
    float* out = (float*)d_out;

    float* ws = (float*)d_ws;
    // floats; live-range-aware:
    // [0,1572864): phase A = xnbf | qb | qbf ; phase B (MLP) = h1bf
    unsigned short* xnbf = (unsigned short*)ws;                  // (B,L,C) bf16
    float*          qb   = ws + 393216;                          // (B,C,L) f32
    unsigned short* qbf  = (unsigned short*)(ws + 1179648);      // (B,NH,L,32) bf16
    unsigned short* h1bf = (unsigned short*)ws;                  // (B*L,HID) bf16 (overlay)
    float* odw   = ws + 1572864;                                 // (BG,CG,L) f32
    unsigned short* xln2bf = (unsigned short*)(ws + 1572864);    // overlay odw
    float* posb  = ws + 2359296;                                 // (BG,NS,2) f32
    unsigned short* xsbf = (unsigned short*)(ws + 2383872);      // (B,NS,C) bf16
    unsigned short* kbf  = (unsigned short*)(ws + 2777088);      // (B,NS,C) bf16
    unsigned short* vtb  = (unsigned short*)(ws + 3170304);      // (B,C,NS) bf16
    unsigned short* attnbf = (unsigned short*)(ws + 3563520);    // (B,L,C) bf16
    float* x2    = ws + 3956736;                                 // (B,L,C) f32
    unsigned short* wqbf   = (unsigned short*)(ws + 4743168);
    unsigned short* wkbf   = (unsigned short*)(ws + 4816896);
    unsigned short* wvbf   = (unsigned short*)(ws + 4890624);
    unsigned short* wobf   = (unsigned short*)(ws + 4964352);
    unsigned short* fc1wbf = (unsigned short*)(ws + 5038080);
    unsigned short* fc2wbf = (unsigned short*)(ws + 5332992);

    // 0. weight casts
    cast_kernel<<<(Cc * Cc + 1023) / 1024, 256, 0, stream>>>(wq, wqbf, Cc * Cc);
    cast_kernel<<<(Cc * Cc + 1023) / 1024, 256, 0, stream>>>(wk, wkbf, Cc * Cc);
    cast_kernel<<<(Cc * Cc + 1023) / 1024, 256, 0, stream>>>(wv, wvbf, Cc * Cc);
    cast_kernel<<<(Cc * Cc + 1023) / 1024, 256, 0, stream>>>(wo, wobf, Cc * Cc);
    cast_kernel<<<(Cc * HIDc + 1023) / 1024, 256, 0, stream>>>(fc1w, fc1wbf, Cc * HIDc);
    cast_kernel<<<(Cc * HIDc + 1023) / 1024, 256, 0, stream>>>(fc2w, fc2wbf, Cc * HIDc);
    // 1. LN1 -> bf16
    ln_kernel<<<Bc * Lc, 128, 0, stream>>>(x, n1w, n1b, xnbf);
    // 2. q projection (MFMA): dual-store f32 (B,C,L) + bf16 (B,NH,L,32)
    mfma_gemm<3><<<dim3(Bc * Lc / 64, Cc / 64), 256, 0, stream>>>(
        xnbf, wqbf, bq, x, qb, qbf, Bc * Lc, Cc, Cc);
    // 3. depthwise 7x7
    dwconv_kernel<<<dim3(CGc, BGc), 256, 0, stream>>>(qb, dw_w, dw_b, odw);
    // 4. offset head -> pos
    offset_kernel<<<dim3(Lc, BGc), 64, 0, stream>>>(odw, lnw, lnb, pw_w, posb);
    // 5. grid-sample xnbf -> xsbf (B, NS, C)
    sample_kernel<<<dim3(NSc / 4, BGc), 256, 0, stream>>>(xnbf, posb, xsbf);
    // 6. k projection (MFMA) -> bf16 (B, NS, C)
    mfma_gemm<4><<<dim3(Bc * NSc / 64, Cc / 64), 256, 0, stream>>>(
        xsbf, wkbf, bk, x, kbf, kbf, Bc * NSc, Cc, Cc);
    // 7. v projection (MFMA) -> bf16 (B, C, NS)
    mfma_gemm<5><<<dim3(Bc * NSc / 64, Cc / 64), 256, 0, stream>>>(
        xsbf, wvbf, bv, x, vtb, vtb, Bc * NSc, Cc, Cc);
    // 8. MFMA flash attention -> bf16 (B,L,C)
    attn_kernel<<<dim3(Lc / 16, NHc, Bc), 256, 0, stream>>>(
        qbf, kbf, vtb, posb, rpe, attnbf);
    // 9. out projection + residual (MFMA) -> x2 f32 (B,L,C)
    mfma_gemm<2><<<dim3(Bc * Lc / 64, Cc / 64), 256, 0, stream>>>(
        attnbf, wobf, bo, x, x2, x2, Bc * Lc, Cc, Cc);
    // 10. LN2 -> bf16
    ln_kernel<<<Bc * Lc, 128, 0, stream>>>(x2, n2w, n2b, xln2bf);
    // 11. fc1 + GELU (MFMA) -> h1 bf16
    mfma_gemm<1><<<dim3(Bc * Lc / 64, HIDc / 64), 256, 0, stream>>>(
        xln2bf, fc1wbf, fc1b, x2, h1bf, h1bf, Bc * Lc, HIDc, Cc);
    // 12. fc2 + residual (MFMA) -> out f32
    mfma_gemm<2><<<dim3(Bc * Lc / 64, Cc / 64), 256, 0, stream>>>(
        h1bf, fc2wbf, fc2b, x2, out, out, Bc * Lc, Cc, HIDc);
}

// Round 7
// 298.142 us; speedup vs baseline: 2.4211x; 1.1130x over previous
//
#include <hip/hip_runtime.h>
#include <math.h>

#define Bc 2
#define Hh 32
#define Ww 32
#define Cc 384
#define NHc 12
#define NGc 6
#define CGc 64
#define HCc 32
#define GHc 2
#define HIDc 1536
#define Lc 1024
#define NSc 1024
#define BGc 12

typedef float f32x4 __attribute__((ext_vector_type(4)));
typedef short bf16x8 __attribute__((ext_vector_type(8)));

__device__ __forceinline__ float gelu_f(float v) {
    return 0.5f * v * (1.f + erff(v * 0.70710678118654752440f));
}

__device__ __forceinline__ unsigned short f2bf(float f) {
    unsigned u = __float_as_uint(f);
    u = (u + 0x7FFF + ((u >> 16) & 1)) >> 16;   // RNE
    return (unsigned short)u;
}

__device__ __forceinline__ float bf2f(unsigned short u) {
    return __uint_as_float((unsigned)u << 16);
}

// ---------------- LayerNorm over C=384 -> bf16, one row per 128 thr -----
__global__ __launch_bounds__(128) void ln_kernel(
    const float* __restrict__ x, const float* __restrict__ w,
    const float* __restrict__ b, unsigned short* __restrict__ out)
{
    __shared__ float l1[2], l2[2];
    int row = blockIdx.x;
    int t = threadIdx.x;
    const float* xr = x + (size_t)row * Cc;
    float v0 = xr[t], v1 = xr[t + 128], v2 = xr[t + 256];
    float s = v0 + v1 + v2;
    #pragma unroll
    for (int o = 32; o; o >>= 1) s += __shfl_down(s, o);
    if ((t & 63) == 0) l1[t >> 6] = s;
    __syncthreads();
    float mu = (l1[0] + l1[1]) * (1.f / Cc);
    float d0 = v0 - mu, d1 = v1 - mu, d2 = v2 - mu;
    float q = d0 * d0 + d1 * d1 + d2 * d2;
    #pragma unroll
    for (int o = 32; o; o >>= 1) q += __shfl_down(q, o);
    if ((t & 63) == 0) l2[t >> 6] = q;
    __syncthreads();
    float rstd = rsqrtf((l2[0] + l2[1]) * (1.f / Cc) + 1e-5f);
    unsigned short* orow = out + (size_t)row * Cc;
    orow[t]       = f2bf(d0 * rstd * w[t]       + b[t]);
    orow[t + 128] = f2bf(d1 * rstd * w[t + 128] + b[t + 128]);
    orow[t + 256] = f2bf(d2 * rstd * w[t + 256] + b[t + 256]);
}

// ---------------- all 6 weight casts in one kernel ----------------------
__global__ __launch_bounds__(256) void cast6_kernel(
    const float* __restrict__ wq, const float* __restrict__ wk,
    const float* __restrict__ wv, const float* __restrict__ wo,
    const float* __restrict__ f1, const float* __restrict__ f2,
    unsigned short* __restrict__ dq, unsigned short* __restrict__ dk,
    unsigned short* __restrict__ dv, unsigned short* __restrict__ d_o,
    unsigned short* __restrict__ d1, unsigned short* __restrict__ d2)
{
    int bid = blockIdx.x;
    const float* s; unsigned short* d; int base;
    if (bid < 144)       { s = wq; d = dq;  base = bid; }
    else if (bid < 288)  { s = wk; d = dk;  base = bid - 144; }
    else if (bid < 432)  { s = wv; d = dv;  base = bid - 288; }
    else if (bid < 576)  { s = wo; d = d_o; base = bid - 432; }
    else if (bid < 1152) { s = f1; d = d1;  base = bid - 576; }
    else                 { s = f2; d = d2;  base = bid - 1152; }
    int i = base * 1024 + threadIdx.x * 4;
    float4 v = *(const float4*)(s + i);
    ushort4 u;
    u.x = f2bf(v.x); u.y = f2bf(v.y); u.z = f2bf(v.z); u.w = f2bf(v.w);
    *(ushort4*)(d + i) = u;
}

// ---------------- bf16 MFMA GEMM v2: wave tile 16m x 32n ----------------
// Block 256 (4 waves stacked in m, 64 m total); grid (M/64, N/32).
// EPI 1: gelu -> bf16 out1[m*N+n]
// EPI 2: + res[m*N+n] -> f32 out1[m*N+n]
// EPI 3: dual q-store: out1 f32 (B,C,L), out2 bf16 (B,NH,L,32)  (b=m>>10)
template<int EPI>
__global__ __launch_bounds__(256) void mfma_gemm(
    const unsigned short* __restrict__ A, const unsigned short* __restrict__ W,
    const float* __restrict__ bias, const float* __restrict__ res,
    void* __restrict__ out1, void* __restrict__ out2, int M, int N, int K)
{
    int w = threadIdx.x >> 6, l = threadIdx.x & 63;
    int col = l & 15, quad = l >> 4;
    int mb = blockIdx.x * 64 + w * 16;
    int n0 = blockIdx.y * 32;
    const unsigned short* Ap = A + (size_t)(mb + col) * K + quad * 8;
    const unsigned short* Wp0 = W + (size_t)(n0 + col) * K + quad * 8;
    const unsigned short* Wp1 = W + (size_t)(n0 + 16 + col) * K + quad * 8;
    f32x4 acc[2] = {};
    #pragma unroll 4
    for (int k0 = 0; k0 < K; k0 += 32) {
        bf16x8 af = *(const bf16x8*)(Ap + k0);
        bf16x8 w0 = *(const bf16x8*)(Wp0 + k0);
        bf16x8 w1 = *(const bf16x8*)(Wp1 + k0);
        acc[0] = __builtin_amdgcn_mfma_f32_16x16x32_bf16(af, w0, acc[0], 0, 0, 0);
        acc[1] = __builtin_amdgcn_mfma_f32_16x16x32_bf16(af, w1, acc[1], 0, 0, 0);
    }
    int bb = mb >> 10, l0 = (mb & 1023) + quad * 4;
    #pragma unroll
    for (int ch = 0; ch < 2; ch++) {
        int n = n0 + ch * 16 + col;
        float bv = bias[n];
        if (EPI == 3) {
            float4 qv;
            qv.x = acc[ch][0] + bv; qv.y = acc[ch][1] + bv;
            qv.z = acc[ch][2] + bv; qv.w = acc[ch][3] + bv;
            *(float4*)&((float*)out1)[((size_t)(bb * Cc + n)) * Lc + l0] = qv;
            unsigned short* q2 = (unsigned short*)out2;
            size_t base = (((size_t)(bb * NHc + (n >> 5))) * Lc + l0) * 32 + (n & 31);
            q2[base]      = f2bf(qv.x);
            q2[base + 32] = f2bf(qv.y);
            q2[base + 64] = f2bf(qv.z);
            q2[base + 96] = f2bf(qv.w);
        } else {
            #pragma unroll
            for (int r = 0; r < 4; r++) {
                size_t m = mb + quad * 4 + r;
                float v = acc[ch][r] + bv;
                if (EPI == 1)
                    ((unsigned short*)out1)[m * N + n] = f2bf(gelu_f(v));
                else
                    ((float*)out1)[m * N + n] = v + res[m * N + n];
            }
        }
    }
}

// ---------------- fused k+v projection (shared A fragments) -------------
// k -> bf16 (B,NS,C) row-major; v -> bf16 (B,C,NS) transposed.
__global__ __launch_bounds__(256) void mfma_kv(
    const unsigned short* __restrict__ A, const unsigned short* __restrict__ Wk,
    const unsigned short* __restrict__ Wv, const float* __restrict__ bk,
    const float* __restrict__ bv, unsigned short* __restrict__ kout,
    unsigned short* __restrict__ vout, int M, int K)
{
    int w = threadIdx.x >> 6, l = threadIdx.x & 63;
    int col = l & 15, quad = l >> 4;
    int mb = blockIdx.x * 64 + w * 16;
    int n0 = blockIdx.y * 32;
    const unsigned short* Ap = A + (size_t)(mb + col) * K + quad * 8;
    const unsigned short* Wk0 = Wk + (size_t)(n0 + col) * K + quad * 8;
    const unsigned short* Wk1 = Wk + (size_t)(n0 + 16 + col) * K + quad * 8;
    const unsigned short* Wv0 = Wv + (size_t)(n0 + col) * K + quad * 8;
    const unsigned short* Wv1 = Wv + (size_t)(n0 + 16 + col) * K + quad * 8;
    f32x4 ak[2] = {}, av[2] = {};
    #pragma unroll 4
    for (int k0 = 0; k0 < K; k0 += 32) {
        bf16x8 af = *(const bf16x8*)(Ap + k0);
        bf16x8 k0f = *(const bf16x8*)(Wk0 + k0);
        bf16x8 k1f = *(const bf16x8*)(Wk1 + k0);
        bf16x8 v0f = *(const bf16x8*)(Wv0 + k0);
        bf16x8 v1f = *(const bf16x8*)(Wv1 + k0);
        ak[0] = __builtin_amdgcn_mfma_f32_16x16x32_bf16(af, k0f, ak[0], 0, 0, 0);
        ak[1] = __builtin_amdgcn_mfma_f32_16x16x32_bf16(af, k1f, ak[1], 0, 0, 0);
        av[0] = __builtin_amdgcn_mfma_f32_16x16x32_bf16(af, v0f, av[0], 0, 0, 0);
        av[1] = __builtin_amdgcn_mfma_f32_16x16x32_bf16(af, v1f, av[1], 0, 0, 0);
    }
    int bb = mb >> 10, l0 = (mb & 1023) + quad * 4;
    #pragma unroll
    for (int ch = 0; ch < 2; ch++) {
        int n = n0 + ch * 16 + col;
        float bkv = bk[n], bvv = bv[n];
        #pragma unroll
        for (int r = 0; r < 4; r++)
            kout[(size_t)(mb + quad * 4 + r) * Cc + n] = f2bf(ak[ch][r] + bkv);
        ushort4 u;
        u.x = f2bf(av[ch][0] + bvv); u.y = f2bf(av[ch][1] + bvv);
        u.z = f2bf(av[ch][2] + bvv); u.w = f2bf(av[ch][3] + bvv);
        *(ushort4*)&vout[((size_t)(bb * Cc + n)) * NSc + l0] = u;
    }
}

// ---------------- Depthwise 7x7 conv (per group-channel), LDS-staged -----
__global__ __launch_bounds__(256) void dwconv_kernel(
    const float* __restrict__ q, const float* __restrict__ wdw,
    const float* __restrict__ bdw, float* __restrict__ o_dw)
{
    int cg = blockIdx.x, bg = blockIdx.y;
    int b = bg / NGc, g = bg % NGc;
    __shared__ float wk_s[49];
    __shared__ float img[1024];
    const float* qp = q + (size_t)(b * Cc + g * CGc + cg) * Lc;
    if (threadIdx.x < 49) wk_s[threadIdx.x] = wdw[cg * 49 + threadIdx.x];
    #pragma unroll
    for (int i = 0; i < 4; i++) img[threadIdx.x + i * 256] = qp[threadIdx.x + i * 256];
    __syncthreads();
    float bias = bdw[cg];
    #pragma unroll
    for (int i = 0; i < 4; i++) {
        int hw = threadIdx.x + i * 256;
        int y = hw >> 5, xx = hw & 31;
        float acc = bias;
        #pragma unroll
        for (int ky = 0; ky < 7; ky++) {
            int yy = y + ky - 3;
            if (yy < 0 || yy > 31) continue;
            #pragma unroll
            for (int kx = 0; kx < 7; kx++) {
                int x2 = xx + kx - 3;
                if (x2 < 0 || x2 > 31) continue;
                acc += img[yy * 32 + x2] * wk_s[ky * 7 + kx];
            }
        }
        o_dw[(size_t)(bg * CGc + cg) * Lc + hw] = acc;
    }
}

// ---------------- LN(CG) + GELU + pointwise -> tanh -> pos ---------------
// 4 waves/block; each wave one hw.
__global__ __launch_bounds__(256) void offset_kernel(
    const float* __restrict__ o_dw, const float* __restrict__ lnw,
    const float* __restrict__ lnb, const float* __restrict__ pw,
    float* __restrict__ pos)
{
    int hw = blockIdx.x * 4 + (threadIdx.x >> 6);
    int bg = blockIdx.y;
    int cg = threadIdx.x & 63;
    float v = o_dw[(size_t)(bg * CGc + cg) * Lc + hw];
    float s = v;
    #pragma unroll
    for (int o = 32; o; o >>= 1) s += __shfl_down(s, o);
    s = __shfl(s, 0, 64);
    float mu = s * (1.f / CGc);
    float d = v - mu;
    float q2 = d * d;
    #pragma unroll
    for (int o = 32; o; o >>= 1) q2 += __shfl_down(q2, o);
    q2 = __shfl(q2, 0, 64);
    float rstd = rsqrtf(q2 * (1.f / CGc) + 1e-5f);
    float t = d * rstd * lnw[cg] + lnb[cg];
    float gl = gelu_f(t);
    float sy = gl * pw[cg];
    float sx = gl * pw[CGc + cg];
    #pragma unroll
    for (int o = 32; o; o >>= 1) {
        sy += __shfl_down(sy, o);
        sx += __shfl_down(sx, o);
    }
    if (cg == 0) {
        float offy = tanhf(sy) * 0.0625f;
        float offx = tanhf(sx) * 0.0625f;
        int y = hw >> 5, xx = hw & 31;
        pos[((size_t)bg * Lc + hw) * 2 + 0] = offy + ((y + 0.5f) * (2.f / Hh) - 1.f);
        pos[((size_t)bg * Lc + hw) * 2 + 1] = offx + ((xx + 0.5f) * (2.f / Ww) - 1.f);
    }
}

// ---------------- bilinear grid-sample of xn(bf16) at pos -> xs bf16 -----
__global__ __launch_bounds__(256) void sample_kernel(
    const unsigned short* __restrict__ xn, const float* __restrict__ pos,
    unsigned short* __restrict__ xs)
{
    int cg = threadIdx.x & 63;
    int nl = threadIdx.x >> 6;
    int n = blockIdx.x * 4 + nl;
    int bg = blockIdx.y;
    int b = bg / NGc, g = bg % NGc;
    float py = pos[((size_t)bg * NSc + n) * 2 + 0];
    float px = pos[((size_t)bg * NSc + n) * 2 + 1];
    float fx = (px + 1.f) * 0.5f * 31.f;
    float fy = (py + 1.f) * 0.5f * 31.f;
    float x0f = floorf(fx), y0f = floorf(fy);
    int x0 = (int)x0f, y0 = (int)y0f;
    float wx1 = fx - x0f, wy1 = fy - y0f;
    float wx0 = 1.f - wx1, wy0 = 1.f - wy1;
    const unsigned short* base = xn + (size_t)(b * Lc) * Cc + g * CGc + cg;
    float acc = 0.f;
    if (y0 >= 0 && y0 <= 31) {
        if (x0 >= 0 && x0 <= 31) acc += bf2f(base[(size_t)(y0 * 32 + x0) * Cc]) * wx0 * wy0;
        if (x0 + 1 >= 0 && x0 + 1 <= 31) acc += bf2f(base[(size_t)(y0 * 32 + x0 + 1) * Cc]) * wx1 * wy0;
    }
    if (y0 + 1 >= 0 && y0 + 1 <= 31) {
        if (x0 >= 0 && x0 <= 31) acc += bf2f(base[(size_t)((y0 + 1) * 32 + x0) * Cc]) * wx0 * wy1;
        if (x0 + 1 >= 0 && x0 + 1 <= 31) acc += bf2f(base[(size_t)((y0 + 1) * 32 + x0 + 1) * Cc]) * wx1 * wy1;
    }
    xs[((size_t)(b * NSc) + n) * Cc + g * CGc + cg] = f2bf(acc);
}

// ---------------- MFMA flash attention v4 (exp2 domain, bf16 RPE) --------
// Block = 256 thr (4 waves) per (b, h, 16 m-rows). Wave w covers n in
// [w*256, w*256+256). RPE table bf16*log2e in LDS (18 KB total -> 8 blk/CU).
__global__ __launch_bounds__(256) void attn_kernel(
    const unsigned short* __restrict__ qbf, const unsigned short* __restrict__ kbf,
    const unsigned short* __restrict__ vtb, const float* __restrict__ pos,
    const float* __restrict__ rpe, unsigned short* __restrict__ attno)
{
    __shared__ float o_smem[2112];               // o_s overlay [4][16][33]
    __shared__ unsigned short p_bf[4][16 * 72];  // per-wave P tile
    __shared__ float ml_s[4][2][16];
    unsigned short* rpe_s = (unsigned short*)o_smem;  // [63][65] bf16*log2e

    int m0 = blockIdx.x * 16;
    int h = blockIdx.y, b = blockIdx.z;
    int tid = threadIdx.x;
    int w = tid >> 6, l = tid & 63;
    int col = l & 15, quad = l >> 4;

    const float* tb = rpe + (size_t)h * 3969;
    for (int i = tid; i < 63 * 65; i += 256) {
        int row = i / 65, cx = i - row * 65;
        rpe_s[i] = (cx < 63) ? f2bf(tb[row * 63 + cx] * 1.44269504f) : 0;
    }

    bf16x8 qfrag = *(const bf16x8*)(qbf +
        ((((size_t)(b * NHc + h)) * Lc + m0 + col) * 32 + quad * 8));

    float qgy = ((m0 >> 5) + 0.5f) * (2.f / 32.f) - 1.f;
    float qgx0 = (((m0 & 31) + quad * 4) + 0.5f) * (2.f / 32.f) - 1.f;

    const unsigned short* kb_ = kbf + (size_t)b * NSc * Cc + h * HCc;
    const unsigned short* vb_ = vtb + ((size_t)(b * Cc + h * HCc)) * NSc;
    const float2* pp = (const float2*)(pos + (size_t)(b * NGc + (h >> 1)) * NSc * 2);

    float run_m[4] = {-3.0e38f, -3.0e38f, -3.0e38f, -3.0e38f};
    float run_l[4] = {0.f, 0.f, 0.f, 0.f};
    f32x4 O0 = {0.f, 0.f, 0.f, 0.f};
    f32x4 O1 = {0.f, 0.f, 0.f, 0.f};

    __syncthreads();   // rpe_s staged

    for (int it = 0; it < 4; it++) {
        int n0 = w * 256 + it * 64;
        // ---- QK^T ----
        f32x4 s[4];
        #pragma unroll
        for (int ch = 0; ch < 4; ch++) {
            bf16x8 kf = *(const bf16x8*)(kb_ +
                ((size_t)(n0 + ch * 16 + col) * Cc + quad * 8));
            f32x4 z = {0.f, 0.f, 0.f, 0.f};
            s[ch] = __builtin_amdgcn_mfma_f32_16x16x32_bf16(qfrag, kf, z, 0, 0, 0);
        }
        // ---- scale(log2e) + RPE bias from bf16 LDS table ----
        #pragma unroll
        for (int ch = 0; ch < 4; ch++) {
            int n = n0 + ch * 16 + col;
            float2 pyx = pp[n];
            float fy = ((qgy - pyx.x) * 0.5f + 1.f) * 31.f;
            float y0f = floorf(fy);
            int iy = (int)y0f;
            float wy1 = fy - y0f, wy0 = 1.f - wy1;
            bool y0ok = (unsigned)iy <= 62u;
            bool y1ok = (unsigned)(iy + 1) <= 62u;
            const unsigned short* r0 = rpe_s + iy * 65;
            float fx0 = ((qgx0 - pyx.y) * 0.5f + 1.f) * 31.f;
            #pragma unroll
            for (int r = 0; r < 4; r++) {
                float fx = fx0 + r * 0.96875f;
                float x0f = floorf(fx);
                int ix = (int)x0f;
                float wx1 = fx - x0f, wx0 = 1.f - wx1;
                bool x0ok = (unsigned)ix <= 62u;
                bool x1ok = (unsigned)(ix + 1) <= 62u;
                float bias = 0.f;
                if (y0ok) {
                    if (x0ok) bias += bf2f(r0[ix]) * wy0 * wx0;
                    if (x1ok) bias += bf2f(r0[ix + 1]) * wy0 * wx1;
                }
                if (y1ok) {
                    if (x0ok) bias += bf2f(r0[65 + ix]) * wy1 * wx0;
                    if (x1ok) bias += bf2f(r0[65 + ix + 1]) * wy1 * wx1;
                }
                // 0.17677669529663688 * log2(e)
                s[ch][r] = s[ch][r] * 0.25506974f + bias;
            }
        }
        // ---- online softmax in exp2 domain (16-lane xor shuffles) ----
        float nm[4], alpha[4];
        #pragma unroll
        for (int r = 0; r < 4; r++) {
            float mx = fmaxf(fmaxf(s[0][r], s[1][r]), fmaxf(s[2][r], s[3][r]));
            #pragma unroll
            for (int msk = 1; msk < 16; msk <<= 1)
                mx = fmaxf(mx, __shfl_xor(mx, msk));
            nm[r] = fmaxf(run_m[r], mx);
            alpha[r] = exp2f(run_m[r] - nm[r]);
            run_m[r] = nm[r];
        }
        float rowsum[4] = {0.f, 0.f, 0.f, 0.f};
        #pragma unroll
        for (int ch = 0; ch < 4; ch++)
            #pragma unroll
            for (int r = 0; r < 4; r++) {
                float e = exp2f(s[ch][r] - nm[r]);
                s[ch][r] = e;
                rowsum[r] += e;
            }
        #pragma unroll
        for (int r = 0; r < 4; r++) {
            float sm = rowsum[r];
            #pragma unroll
            for (int msk = 1; msk < 16; msk <<= 1)
                sm += __shfl_xor(sm, msk);
            run_l[r] = run_l[r] * alpha[r] + sm;
        }
        // ---- P -> wave-private LDS (C-layout -> A-layout) ----
        #pragma unroll
        for (int ch = 0; ch < 4; ch++)
            #pragma unroll
            for (int r = 0; r < 4; r++)
                p_bf[w][(quad * 4 + r) * 72 + ch * 16 + col] = f2bf(s[ch][r]);
        // ---- rescale O, PV ----
        #pragma unroll
        for (int r = 0; r < 4; r++) { O0[r] *= alpha[r]; O1[r] *= alpha[r]; }
        #pragma unroll
        for (int half = 0; half < 2; half++) {
            bf16x8 pf = *(const bf16x8*)&p_bf[w][col * 72 + half * 32 + quad * 8];
            bf16x8 v0 = *(const bf16x8*)(vb_ +
                ((size_t)col * NSc + n0 + half * 32 + quad * 8));
            O0 = __builtin_amdgcn_mfma_f32_16x16x32_bf16(pf, v0, O0, 0, 0, 0);
            bf16x8 v1 = *(const bf16x8*)(vb_ +
                ((size_t)(col + 16) * NSc + n0 + half * 32 + quad * 8));
            O1 = __builtin_amdgcn_mfma_f32_16x16x32_bf16(pf, v1, O1, 0, 0, 0);
        }
    }
    __syncthreads();   // all rpe_s reads done before o_s overlay
    float* o_s = o_smem;
    #pragma unroll
    for (int r = 0; r < 4; r++) {
        int m = quad * 4 + r;
        o_s[w * 528 + m * 33 + col] = O0[r];
        o_s[w * 528 + m * 33 + col + 16] = O1[r];
    }
    if (col == 0) {
        #pragma unroll
        for (int r = 0; r < 4; r++) {
            ml_s[w][0][quad * 4 + r] = run_m[r];
            ml_s[w][1][quad * 4 + r] = run_l[r];
        }
    }
    __syncthreads();
    // ---- cross-wave merge (exp2 domain) -> bf16 (B,L,C) ----
    for (int i = tid; i < 512; i += 256) {
        int m = i >> 5, c = i & 31;
        float fm = fmaxf(fmaxf(ml_s[0][0][m], ml_s[1][0][m]),
                         fmaxf(ml_s[2][0][m], ml_s[3][0][m]));
        float lsum = 0.f, osum = 0.f;
        #pragma unroll
        for (int ww = 0; ww < 4; ww++) {
            float sc = exp2f(ml_s[ww][0][m] - fm);
            lsum += ml_s[ww][1][m] * sc;
            osum += o_s[ww * 528 + m * 33 + c] * sc;
        }
        attno[((size_t)(b * Lc) + m0 + m) * Cc + h * HCc + c] = f2bf(osum / lsum);
    }
}

extern "C" void kernel_launch(void* const* d_in, const int* in_sizes, int n_in,
                              void* d_out, int out_size, void* d_ws, size_t ws_size,
                              hipStream_t stream)
{
    const float* x    = (const float*)d_in[0];
    const float* n1w  = (const float*)d_in[1];
    const float* n1b  = (const float*)d_in[2];
    const float* wq   = (const float*)d_in[3];
    const float* bq   = (const float*)d_in[4];
    const float* wk   = (const float*)d_in[5];
    const float* bk   = (const float*)d_in[6];
    const float* wv   = (const float*)d_in[7];
    const float* bv   = (const float*)d_in[8];
    const float* wo   = (const float*)d_in[9];
    const float* bo   = (const float*)d_in[10];
    const float* dw_w = (const float*)d_in[11];
    const float* dw_b = (const float*)d_in[12];
    const float* lnw  = (const float*)d_in[13];
    const float* lnb  = (const float*)d_in[14];
    const float* pw_w = (const float*)d_in[15];
    const float* rpe  = (const float*)d_in[16];
    const float* n2w  = (const float*)d_in[17];
    const float* n2b  = (const float*)d_in[18];
    const float* fc1w = (const float*)d_in[19];
    const float* fc1b = (const float*)d_in[20];
    const float* fc2w = (const float*)d_in[21];
    const float* fc2b = (const float*)d_in[22];
    float* out = (float*)d_out;

    float* ws = (float*)d_ws;
    // floats; live-range-aware:
    unsigned short* xnbf = (unsigned short*)ws;                  // (B,L,C) bf16
    float*          qb   = ws + 393216;                          // (B,C,L) f32
    unsigned short* qbf  = (unsigned short*)(ws + 1179648);      // (B,NH,L,32) bf16
    unsigned short* h1bf = (unsigned short*)ws;                  // (B*L,HID) bf16 (overlay)
    float* odw   = ws + 1572864;                                 // (BG,CG,L) f32
    unsigned short* xln2bf = (unsigned short*)(ws + 1572864);    // overlay odw
    float* posb  = ws + 2359296;                                 // (BG,NS,2) f32
    unsigned short* xsbf = (unsigned short*)(ws + 2383872);      // (B,NS,C) bf16
    unsigned short* kbf  = (unsigned short*)(ws + 2777088);      // (B,NS,C) bf16
    unsigned short* vtb  = (unsigned short*)(ws + 3170304);      // (B,C,NS) bf16
    unsigned short* attnbf = (unsigned short*)(ws + 3563520);    // (B,L,C) bf16
    float* x2    = ws + 3956736;                                 // (B,L,C) f32
    unsigned short* wqbf   = (unsigned short*)(ws + 4743168);
    unsigned short* wkbf   = (unsigned short*)(ws + 4816896);
    unsigned short* wvbf   = (unsigned short*)(ws + 4890624);
    unsigned short* wobf   = (unsigned short*)(ws + 4964352);
    unsigned short* fc1wbf = (unsigned short*)(ws + 5038080);
    unsigned short* fc2wbf = (unsigned short*)(ws + 5332992);

    // 0. all weight casts (1 launch)
    cast6_kernel<<<1728, 256, 0, stream>>>(
        wq, wk, wv, wo, fc1w, fc2w, wqbf, wkbf, wvbf, wobf, fc1wbf, fc2wbf);
    // 1. LN1 -> bf16
    ln_kernel<<<Bc * Lc, 128, 0, stream>>>(x, n1w, n1b, xnbf);
    // 2. q projection (MFMA): dual-store f32 (B,C,L) + bf16 (B,NH,L,32)
    mfma_gemm<3><<<dim3(Bc * Lc / 64, Cc / 32), 256, 0, stream>>>(
        xnbf, wqbf, bq, x, qb, qbf, Bc * Lc, Cc, Cc);
    // 3. depthwise 7x7
    dwconv_kernel<<<dim3(CGc, BGc), 256, 0, stream>>>(qb, dw_w, dw_b, odw);
    // 4. offset head -> pos
    offset_kernel<<<dim3(Lc / 4, BGc), 256, 0, stream>>>(odw, lnw, lnb, pw_w, posb);
    // 5. grid-sample xnbf -> xsbf (B, NS, C)
    sample_kernel<<<dim3(NSc / 4, BGc), 256, 0, stream>>>(xnbf, posb, xsbf);
    // 6. fused k+v projection
    mfma_kv<<<dim3(Bc * NSc / 64, Cc / 32), 256, 0, stream>>>(
        xsbf, wkbf, wvbf, bk, bv, kbf, vtb, Bc * NSc, Cc);
    // 7. MFMA flash attention -> bf16 (B,L,C)
    attn_kernel<<<dim3(Lc / 16, NHc, Bc), 256, 0, stream>>>(
        qbf, kbf, vtb, posb, rpe, attnbf);
    // 8. out projection + residual (MFMA) -> x2 f32 (B,L,C)
    mfma_gemm<2><<<dim3(Bc * Lc / 64, Cc / 32), 256, 0, stream>>>(
        attnbf, wobf, bo, x, x2, x2, Bc * Lc, Cc, Cc);
    // 9. LN2 -> bf16
    ln_kernel<<<Bc * Lc, 128, 0, stream>>>(x2, n2w, n2b, xln2bf);
    // 10. fc1 + GELU (MFMA) -> h1 bf16
    mfma_gemm<1><<<dim3(Bc * Lc / 64, HIDc / 32), 256, 0, stream>>>(
        xln2bf, fc1wbf, fc1b, x2, h1bf, h1bf, Bc * Lc, HIDc, Cc);
    // 11. fc2 + residual (MFMA) -> out f32
    mfma_gemm<2><<<dim3(Bc * Lc / 64, Cc / 32), 256, 0, stream>>>(
        h1bf, fc2wbf, fc2b, x2, out, out, Bc * Lc, Cc, HIDc);
}